// Round 2
// baseline (3803.970 us; speedup 1.0000x reference)
//
#include <hip/hip_runtime.h>
#include <math.h>

typedef unsigned short u16;
typedef unsigned int   u32;

#define NATOMS 8192
#define GRAPHS 64
#define APG    128
#define KNN    32
#define NGAUSS 50
#define HID    128
#define LAYERS 6

__device__ __forceinline__ float bf2f(u16 v) {
    return __uint_as_float(((u32)v) << 16);
}
__device__ __forceinline__ u16 f2bf(float f) {
    u32 u = __float_as_uint(f);
    u32 lsb = (u >> 16) & 1u;
    u += 0x7fffu + lsb;
    return (u16)(u >> 16);
}
__device__ __forceinline__ float silu_f(float x) {
    float s = 1.0f / (1.0f + expf(-x));
    return x * s;
}

// ---------------------------------------------------------------------------
// K0: dtype probe. Even u16 half-words of emb: real bf16 weights if the
// buffer is bf16 (|x|<1), random fp32 mantissa words if fp32 (huge/NaN with
// p~0.46 each). flag=1 -> inputs are fp32.
// ---------------------------------------------------------------------------
__global__ void probe_kernel(const u16* __restrict__ raw, int* __restrict__ flag) {
    __shared__ int s;
    int t = threadIdx.x;
    if (t == 0) s = 0;
    __syncthreads();
    float x = bf2f(raw[2 * t]);
    if (!(fabsf(x) < 1000.0f)) atomicOr(&s, 1);
    __syncthreads();
    if (t == 0) *flag = s;
}

// ---------------------------------------------------------------------------
// K0b: ingest. Converts every float input to a canonical workspace copy
// (fp32 or bf16 per-array), reading source as fp32 or bf16 per the flag.
// ---------------------------------------------------------------------------
#define NARR 14
struct IngestDesc {
    const void* src[NARR];
    void*       dst[NARR];
    int         n[NARR];
    int         to_bf16[NARR];
};

__global__ void ingest_kernel(IngestDesc d, const int* __restrict__ flag, int total) {
    int gid = blockIdx.x * blockDim.x + threadIdx.x;
    if (gid >= total) return;
    int a = 0, off = gid;
    while (off >= d.n[a]) { off -= d.n[a]; ++a; }
    bool f32in = (*flag != 0);
    float v = f32in ? ((const float*)d.src[a])[off]
                    : bf2f(((const u16*)d.src[a])[off]);
    if (d.to_bf16[a]) ((u16*)d.dst[a])[off] = f2bf(v);
    else              ((float*)d.dst[a])[off] = v;
}

// ---------------------------------------------------------------------------
// K1: graph build. One block per graph, one thread per center atom.
// d2 with explicit rn ops (no fma contraction) to match numpy fp32;
// top-32 by (d2, index) lexicographic == jax.lax.top_k tie-breaking.
// LDS row XOR-swizzled to avoid stride-128 bank conflicts.
// ---------------------------------------------------------------------------
__launch_bounds__(128)
__global__ void build_graph_kernel(const float* __restrict__ pos,
                                   int* __restrict__ idx,
                                   float* __restrict__ dist,
                                   float* __restrict__ cvalp) {
    __shared__ float d2s[128 * 128];   // exactly 64 KB
    int g = blockIdx.x, t = threadIdx.x;
    int base = g * APG;
    float cx = pos[(base + t) * 3 + 0];
    float cy = pos[(base + t) * 3 + 1];
    float cz = pos[(base + t) * 3 + 2];
    int sw = t & 31;
    for (int j = 0; j < APG; ++j) {
        float jx = pos[(base + j) * 3 + 0];   // broadcast load, L1-hot
        float jy = pos[(base + j) * 3 + 1];
        float jz = pos[(base + j) * 3 + 2];
        float dx = __fsub_rn(cx, jx);
        float dy = __fsub_rn(cy, jy);
        float dz = __fsub_rn(cz, jz);
        float d2 = __fadd_rn(__fadd_rn(__fmul_rn(dx, dx), __fmul_rn(dy, dy)),
                             __fmul_rn(dz, dz));
        bool valid = (j != t) && (d2 < 100.0f);
        d2s[t * 128 + (j ^ sw)] = valid ? d2 : INFINITY;
    }
    // each thread scans only its own row; no barrier needed
    for (int k = 0; k < KNN; ++k) {
        float best = INFINITY; int bj = -1;
        for (int j = 0; j < APG; ++j) {
            float v = d2s[t * 128 + (j ^ sw)];
            if (v < best || (bj < 0 && v == INFINITY)) { best = v; bj = j; }
        }
        d2s[t * 128 + (bj ^ sw)] = __int_as_float(0x7fc00000);  // NaN = consumed
        bool ev = (best < INFINITY);
        float d = ev ? __fsqrt_rn(best) : 1.0f;
        float cv = 0.0f;
        if (ev && d < 10.0f) cv = 0.5f * (cosf(d * 3.14159265f / 10.0f) + 1.0f);
        int e = (base + t) * KNN + k;
        idx[e]   = base + bj;
        dist[e]  = d;
        cvalp[e] = cv;
    }
}

// ---------------------------------------------------------------------------
// K2: embedding gather, h[i] = emb[z[i]] (canonical fp32)
// ---------------------------------------------------------------------------
__global__ void embed_kernel(const int* __restrict__ z,
                             const float* __restrict__ emb,
                             float* __restrict__ h) {
    int i = blockIdx.x, t = threadIdx.x;
    h[(size_t)i * HID + t] = emb[(size_t)z[i] * HID + t];
}

// ---------------------------------------------------------------------------
// GEMM: O[8192,128] = A[8192,128](fp32) @ B[128,128](bf16) + bias(fp32)
// MODE 0: O = result (xj). MODE 1: O += silu(result) (h update, O=h).
// ---------------------------------------------------------------------------
template <int MODE>
__launch_bounds__(256)
__global__ void gemm_nk128(const float* __restrict__ A,
                           const u16* __restrict__ B,
                           const float* __restrict__ bias,
                           float* __restrict__ O) {
    __shared__ float At[128][36];   // [f][r], padded
    __shared__ u16   Bs[128 * 128];
    __shared__ float bs[128];
    int tid = threadIdx.x;
    int row0 = blockIdx.x * 32;
    for (int p = 0; p < 4; ++p) {
        int v = tid + p * 256;
        int r = v >> 5;
        int f = (v & 31) * 4;
        const float4 a = *(const float4*)(A + (size_t)(row0 + r) * 128 + f);
        At[f + 0][r] = a.x; At[f + 1][r] = a.y;
        At[f + 2][r] = a.z; At[f + 3][r] = a.w;
    }
    {
        const uint4* Bg = (const uint4*)B;
        uint4* Bl = (uint4*)Bs;
        for (int p = 0; p < 8; ++p) Bl[tid + p * 256] = Bg[tid + p * 256];
    }
    if (tid < 128) bs[tid] = bias[tid];
    __syncthreads();

    int c0 = (tid & 31) * 4;
    int r0 = (tid >> 5) * 4;
    float acc[4][4] = {};
    for (int f = 0; f < 128; ++f) {
        float4 a = *(const float4*)&At[f][r0];
        ushort4 b = *(const ushort4*)&Bs[f * 128 + c0];
        float b0 = bf2f(b.x), b1 = bf2f(b.y), b2 = bf2f(b.z), b3 = bf2f(b.w);
        acc[0][0] += a.x * b0; acc[0][1] += a.x * b1; acc[0][2] += a.x * b2; acc[0][3] += a.x * b3;
        acc[1][0] += a.y * b0; acc[1][1] += a.y * b1; acc[1][2] += a.y * b2; acc[1][3] += a.y * b3;
        acc[2][0] += a.z * b0; acc[2][1] += a.z * b1; acc[2][2] += a.z * b2; acc[2][3] += a.z * b3;
        acc[3][0] += a.w * b0; acc[3][1] += a.w * b1; acc[3][2] += a.w * b2; acc[3][3] += a.w * b3;
    }
    for (int ri = 0; ri < 4; ++ri) {
        size_t off = (size_t)(row0 + r0 + ri) * 128 + c0;
        float4 o;
        o.x = acc[ri][0] + bs[c0 + 0];
        o.y = acc[ri][1] + bs[c0 + 1];
        o.z = acc[ri][2] + bs[c0 + 2];
        o.w = acc[ri][3] + bs[c0 + 3];
        if (MODE == 0) {
            *(float4*)(O + off) = o;
        } else {
            float4 hv = *(const float4*)(O + off);
            hv.x += silu_f(o.x); hv.y += silu_f(o.y);
            hv.z += silu_f(o.z); hv.w += silu_f(o.w);
            *(float4*)(O + off) = hv;
        }
    }
}

// ---------------------------------------------------------------------------
// K4: edge kernel. One block per center i (32 edges).
// W = (silu(rbf@mw1+mb1)@mw2+mb2)*cval, msg = xj[i]*W, atomicAdd into agg[j].
// ---------------------------------------------------------------------------
__launch_bounds__(256)
__global__ void edge_kernel(const float* __restrict__ dist,
                            const float* __restrict__ cval,
                            const int* __restrict__ idx,
                            const float* __restrict__ xj,
                            const u16* __restrict__ mw1,
                            const float* __restrict__ mb1,
                            const u16* __restrict__ mw2,
                            const float* __restrict__ mb2,
                            float* __restrict__ agg) {
    __shared__ u16   s_w1[NGAUSS * 128];   // 12.8 KB
    __shared__ u16   s_w2[128 * 128];      // 32 KB
    __shared__ float s_rbf[NGAUSS][36];    // [g][e], padded
    __shared__ u16   s_t1[128][36];        // [f][e] bf16, padded
    __shared__ float s_xj[128];
    __shared__ float s_b1[128], s_b2[128];
    __shared__ float s_cv[KNN], s_d[KNN];
    __shared__ int   s_ix[KNN];

    int tid = threadIdx.x;
    int i = blockIdx.x;

    {
        const uint4* w2g = (const uint4*)mw2;
        uint4* w2l = (uint4*)s_w2;
        for (int p = 0; p < 8; ++p) w2l[tid + p * 256] = w2g[tid + p * 256];
    }
    for (int e = tid; e < NGAUSS * 128; e += 256) s_w1[e] = mw1[e];
    if (tid < 128) {
        s_b1[tid] = mb1[tid];
        s_b2[tid] = mb2[tid];
        s_xj[tid] = xj[(size_t)i * 128 + tid];
    } else if (tid < 128 + KNN) {
        int k = tid - 128;
        int e = i * KNN + k;
        s_d[k]  = dist[e];
        s_cv[k] = cval[e];
        s_ix[k] = idx[e];
    }
    __syncthreads();

    for (int q = tid; q < NGAUSS * KNN; q += 256) {
        int gg = q >> 5;
        int e  = q & 31;
        float off = (10.0f / 49.0f) * (float)gg;
        float tt = (s_d[e] - off) / (10.0f / 49.0f);
        s_rbf[gg][e] = expf(-0.5f * tt * tt);
    }
    __syncthreads();

    int f0 = (tid & 31) * 4;
    int e0 = (tid >> 5) * 4;

    // Phase A: t1[e][f] = silu(sum_g rbf[g][e]*mw1[g][f] + mb1[f])
    {
        float acc[4][4] = {};   // [e][f]
        for (int gg = 0; gg < NGAUSS; ++gg) {
            float4 a = *(const float4*)&s_rbf[gg][e0];
            ushort4 b = *(const ushort4*)&s_w1[gg * 128 + f0];
            float b0 = bf2f(b.x), b1 = bf2f(b.y), b2 = bf2f(b.z), b3 = bf2f(b.w);
            acc[0][0] += a.x * b0; acc[0][1] += a.x * b1; acc[0][2] += a.x * b2; acc[0][3] += a.x * b3;
            acc[1][0] += a.y * b0; acc[1][1] += a.y * b1; acc[1][2] += a.y * b2; acc[1][3] += a.y * b3;
            acc[2][0] += a.z * b0; acc[2][1] += a.z * b1; acc[2][2] += a.z * b2; acc[2][3] += a.z * b3;
            acc[3][0] += a.w * b0; acc[3][1] += a.w * b1; acc[3][2] += a.w * b2; acc[3][3] += a.w * b3;
        }
        for (int c = 0; c < 4; ++c) {
            float bb = s_b1[f0 + c];
            ushort4 t4;
            t4.x = f2bf(silu_f(acc[0][c] + bb));
            t4.y = f2bf(silu_f(acc[1][c] + bb));
            t4.z = f2bf(silu_f(acc[2][c] + bb));
            t4.w = f2bf(silu_f(acc[3][c] + bb));
            *(ushort4*)&s_t1[f0 + c][e0] = t4;
        }
    }
    __syncthreads();

    // Phase B: W[e][f2] = sum_f t1[e][f]*mw2[f][f2]
    {
        float acc[4][4] = {};   // [e][f2]
        for (int f = 0; f < 128; ++f) {
            ushort4 av = *(const ushort4*)&s_t1[f][e0];
            float a0 = bf2f(av.x), a1 = bf2f(av.y), a2 = bf2f(av.z), a3 = bf2f(av.w);
            ushort4 bv = *(const ushort4*)&s_w2[f * 128 + f0];
            float b0 = bf2f(bv.x), b1 = bf2f(bv.y), b2 = bf2f(bv.z), b3 = bf2f(bv.w);
            acc[0][0] += a0 * b0; acc[0][1] += a0 * b1; acc[0][2] += a0 * b2; acc[0][3] += a0 * b3;
            acc[1][0] += a1 * b0; acc[1][1] += a1 * b1; acc[1][2] += a1 * b2; acc[1][3] += a1 * b3;
            acc[2][0] += a2 * b0; acc[2][1] += a2 * b1; acc[2][2] += a2 * b2; acc[2][3] += a2 * b3;
            acc[3][0] += a3 * b0; acc[3][1] += a3 * b1; acc[3][2] += a3 * b2; acc[3][3] += a3 * b3;
        }
        for (int ei = 0; ei < 4; ++ei) {
            float cv = s_cv[e0 + ei];
            int j = s_ix[e0 + ei];
            float* dst = agg + (size_t)j * 128;
            for (int ci = 0; ci < 4; ++ci) {
                int f2 = f0 + ci;
                float W = (acc[ei][ci] + s_b2[f2]) * cv;
                atomicAdd(dst + f2, s_xj[f2] * W);
            }
        }
    }
}

// ---------------------------------------------------------------------------
// K6: output head. One wave per atom.
// ---------------------------------------------------------------------------
__launch_bounds__(64)
__global__ void head_kernel(const float* __restrict__ h,
                            const float* __restrict__ ow1,
                            const float* __restrict__ ob1,
                            const float* __restrict__ ow2,
                            const float* __restrict__ ob2,
                            float* __restrict__ gsum) {
    int i = blockIdx.x;        // atom
    int c = threadIdx.x;       // 0..63
    const float* hrow = h + (size_t)i * 128;
    float o = ob1[c];
    for (int f = 0; f < 128; ++f) o += hrow[f] * ow1[f * 64 + c];
    o = silu_f(o);
    float v = o * ow2[c];
    for (int off = 32; off > 0; off >>= 1) v += __shfl_down(v, off, 64);
    if (c == 0) {
        int g = i >> 7;
        atomicAdd(&gsum[g], v + ob2[0]);
    }
}

__global__ void finalize_kernel(const float* __restrict__ gsum, void* __restrict__ out,
                                const int* __restrict__ flag) {
    int t = threadIdx.x;
    if (*flag) ((float*)out)[t] = gsum[t];
    else       ((u16*)out)[t]   = f2bf(gsum[t]);
}

// ---------------------------------------------------------------------------
extern "C" void kernel_launch(void* const* d_in, const int* in_sizes, int n_in,
                              void* d_out, int out_size, void* d_ws, size_t ws_size,
                              hipStream_t stream) {
    const void* pos  = d_in[0];
    const int*  z    = (const int*)d_in[1];
    // d_in[2] = batch (implicit: graph = i >> 7)
    const void* emb  = d_in[3];
    const void* mw1  = d_in[4];
    const void* mb1  = d_in[5];
    const void* mw2  = d_in[6];
    const void* mb2  = d_in[7];
    const void* l1w  = d_in[8];
    const void* l1b  = d_in[9];
    const void* l2w  = d_in[10];
    const void* l2b  = d_in[11];
    const void* ow1  = d_in[12];
    const void* ob1  = d_in[13];
    const void* ow2  = d_in[14];
    const void* ob2  = d_in[15];

    char* ws = (char*)d_ws;
    const size_t KB = 1024, MB = 1048576;
    int*   w_flag = (int*)  (ws);
    float* c_pos  = (float*)(ws + 4   * KB);   // 24576 f
    float* c_emb  = (float*)(ws + 112 * KB);   // 12800 f
    float* c_mb1  = (float*)(ws + 176 * KB);   // 768 f
    float* c_mb2  = (float*)(ws + 180 * KB);
    float* c_l1b  = (float*)(ws + 184 * KB);
    float* c_l2b  = (float*)(ws + 188 * KB);
    float* c_ow1  = (float*)(ws + 192 * KB);   // 8192 f
    float* c_ob1  = (float*)(ws + 226 * KB);   // 64 f
    float* c_ow2  = (float*)(ws + 227 * KB);   // 64 f
    float* c_ob2  = (float*)(ws + 228 * KB);   // 1 f
    u16*   c_mw1  = (u16*)  (ws + 232 * KB);   // 38400 bf16
    u16*   c_mw2  = (u16*)  (ws + 312 * KB);   // 98304 bf16
    u16*   c_l1w  = (u16*)  (ws + 512 * KB);   // 98304 bf16
    u16*   c_l2w  = (u16*)  (ws + 704 * KB);   // 98304 bf16
    int*   w_idx  = (int*)  (ws + 1  * MB);
    float* w_dist = (float*)(ws + 2  * MB);
    float* w_cval = (float*)(ws + 3  * MB);
    float* w_h    = (float*)(ws + 4  * MB);
    float* w_xj   = (float*)(ws + 8  * MB);
    float* w_agg  = (float*)(ws + 12 * MB);
    float* w_gsum = (float*)(ws + 16 * MB);

    probe_kernel<<<1, 256, 0, stream>>>((const u16*)emb, w_flag);

    IngestDesc dsc;
    const void* srcs[NARR] = {pos, emb, mb1, mb2, l1b, l2b, ow1, ob1, ow2, ob2,
                              mw1, mw2, l1w, l2w};
    void* dsts[NARR] = {c_pos, c_emb, c_mb1, c_mb2, c_l1b, c_l2b, c_ow1, c_ob1,
                        c_ow2, c_ob2, c_mw1, c_mw2, c_l1w, c_l2w};
    int ns[NARR] = {24576, 12800, 768, 768, 768, 768, 8192, 64, 64, 1,
                    38400, 98304, 98304, 98304};
    int tb[NARR] = {0,0,0,0,0,0,0,0,0,0, 1,1,1,1};
    int total = 0;
    for (int a = 0; a < NARR; ++a) {
        dsc.src[a] = srcs[a]; dsc.dst[a] = dsts[a];
        dsc.n[a] = ns[a]; dsc.to_bf16[a] = tb[a];
        total += ns[a];
    }
    ingest_kernel<<<(total + 255) / 256, 256, 0, stream>>>(dsc, w_flag, total);

    build_graph_kernel<<<GRAPHS, APG, 0, stream>>>(c_pos, w_idx, w_dist, w_cval);
    embed_kernel<<<NATOMS, HID, 0, stream>>>(z, c_emb, w_h);

    for (int l = 0; l < LAYERS; ++l) {
        gemm_nk128<0><<<NATOMS / 32, 256, 0, stream>>>(
            w_h, c_l1w + (size_t)l * 128 * 128, c_l1b + (size_t)l * 128, w_xj);
        hipMemsetAsync(w_agg, 0, (size_t)NATOMS * HID * sizeof(float), stream);
        edge_kernel<<<NATOMS, 256, 0, stream>>>(
            w_dist, w_cval, w_idx, w_xj,
            c_mw1 + (size_t)l * NGAUSS * 128, c_mb1 + (size_t)l * 128,
            c_mw2 + (size_t)l * 128 * 128,    c_mb2 + (size_t)l * 128, w_agg);
        gemm_nk128<1><<<NATOMS / 32, 256, 0, stream>>>(
            w_agg, c_l2w + (size_t)l * 128 * 128, c_l2b + (size_t)l * 128, w_h);
    }

    hipMemsetAsync(w_gsum, 0, GRAPHS * sizeof(float), stream);
    head_kernel<<<NATOMS, 64, 0, stream>>>(w_h, c_ow1, c_ob1, c_ow2, c_ob2, w_gsum);
    finalize_kernel<<<1, GRAPHS, 0, stream>>>(w_gsum, (void*)d_out, w_flag);
}

// Round 3
// 1378.632 us; speedup vs baseline: 2.7592x; 2.7592x over previous
//
#include <hip/hip_runtime.h>
#include <math.h>

typedef unsigned short u16;
typedef unsigned int   u32;

#define NATOMS 8192
#define GRAPHS 64
#define APG    128
#define KNN    32
#define NGAUSS 50
#define HID    128
#define LAYERS 6
#define PAD64  72
#define PAD128 136

typedef __attribute__((ext_vector_type(8))) short bf16x8;
typedef __attribute__((ext_vector_type(4))) float f32x4;

__device__ __forceinline__ float bf2f(u16 v) {
    return __uint_as_float(((u32)v) << 16);
}
__device__ __forceinline__ u16 f2bf(float f) {
    u32 u = __float_as_uint(f);
    u32 lsb = (u >> 16) & 1u;
    u += 0x7fffu + lsb;
    return (u16)(u >> 16);
}
__device__ __forceinline__ float silu_f(float x) {
    float s = 1.0f / (1.0f + expf(-x));
    return x * s;
}
__device__ __forceinline__ bf16x8 ldfrag(const u16* p) {
    return *(const bf16x8*)__builtin_assume_aligned(p, 16);
}

// ---------------------------------------------------------------------------
// K0: dtype probe. Even u16 half-words of emb: real bf16 weights if buffer is
// bf16 (|x| small), random fp32 mantissa words if fp32 (huge/NaN p~0.46 each).
// ---------------------------------------------------------------------------
__global__ void probe_kernel(const u16* __restrict__ raw, int* __restrict__ flag) {
    __shared__ int s;
    int t = threadIdx.x;
    if (t == 0) s = 0;
    __syncthreads();
    float x = bf2f(raw[2 * t]);
    if (!(fabsf(x) < 1000.0f)) atomicOr(&s, 1);
    __syncthreads();
    if (t == 0) *flag = s;
}

// ---------------------------------------------------------------------------
// K0b: ingest small fp32-canonical arrays.
// ---------------------------------------------------------------------------
#define NARR 10
struct IngestDesc {
    const void* src[NARR];
    void*       dst[NARR];
    int         n[NARR];
};

__global__ void ingest_kernel(IngestDesc d, const int* __restrict__ flag, int total) {
    int gid = blockIdx.x * blockDim.x + threadIdx.x;
    if (gid >= total) return;
    int a = 0, off = gid;
    while (off >= d.n[a]) { off -= d.n[a]; ++a; }
    bool f32in = (*flag != 0);
    float v = f32in ? ((const float*)d.src[a])[off]
                    : bf2f(((const u16*)d.src[a])[off]);
    ((float*)d.dst[a])[off] = v;
}

// ---------------------------------------------------------------------------
// K0c: weight prep — transpose to [n][k] bf16 for MFMA B-operands.
// l1wt/l2wt/mw2t: [6][128][128]; mw1t: [6][128][64] with k in [50,64) zeroed.
// ---------------------------------------------------------------------------
__global__ void prep_weights(const void* __restrict__ l1w, const void* __restrict__ l2w,
                             const void* __restrict__ mw2, const void* __restrict__ mw1,
                             u16* __restrict__ l1wt, u16* __restrict__ l2wt,
                             u16* __restrict__ mw2t, u16* __restrict__ mw1t,
                             const int* __restrict__ flag) {
    int gid = blockIdx.x * blockDim.x + threadIdx.x;
    bool f32in = (*flag != 0);
    if (gid < 3 * 98304) {
        int seg = gid / 98304;
        int t = gid % 98304;
        int l = t >> 14;
        int n = (t >> 7) & 127;
        int k = t & 127;
        const void* src = (seg == 0) ? l1w : ((seg == 1) ? l2w : mw2);
        u16* dst = (seg == 0) ? l1wt : ((seg == 1) ? l2wt : mw2t);
        int si = l * 16384 + k * 128 + n;
        float v = f32in ? ((const float*)src)[si] : bf2f(((const u16*)src)[si]);
        dst[t] = f2bf(v);
    } else {
        int t = gid - 3 * 98304;
        if (t < 49152) {
            int l = t >> 13;
            int n = (t >> 6) & 127;
            int k = t & 63;
            float v = 0.0f;
            if (k < 50) {
                int si = l * 6400 + k * 128 + n;
                v = f32in ? ((const float*)mw1)[si] : bf2f(((const u16*)mw1)[si]);
            }
            mw1t[t] = f2bf(v);
        }
    }
}

// ---------------------------------------------------------------------------
// K1: graph build + REVERSE adjacency. One block per graph.
// rev_e[j][0..deg) = forward edge ids whose receiver is j (valid edges only,
// cv>0 <=> evalid). In-degree <= 127 < 128 cap. rev_cnt pre-zeroed.
// ---------------------------------------------------------------------------
__launch_bounds__(128)
__global__ void build_graph_kernel(const float* __restrict__ pos,
                                   float* __restrict__ dist,
                                   float* __restrict__ cvalp,
                                   int* __restrict__ rev_cnt,
                                   int* __restrict__ rev_e) {
    __shared__ float d2s[128 * 128];
    int g = blockIdx.x, t = threadIdx.x;
    int base = g * APG;
    float cx = pos[(base + t) * 3 + 0];
    float cy = pos[(base + t) * 3 + 1];
    float cz = pos[(base + t) * 3 + 2];
    int sw = t & 31;
    for (int j = 0; j < APG; ++j) {
        float jx = pos[(base + j) * 3 + 0];
        float jy = pos[(base + j) * 3 + 1];
        float jz = pos[(base + j) * 3 + 2];
        float dx = __fsub_rn(cx, jx);
        float dy = __fsub_rn(cy, jy);
        float dz = __fsub_rn(cz, jz);
        float d2 = __fadd_rn(__fadd_rn(__fmul_rn(dx, dx), __fmul_rn(dy, dy)),
                             __fmul_rn(dz, dz));
        bool valid = (j != t) && (d2 < 100.0f);
        d2s[t * 128 + (j ^ sw)] = valid ? d2 : INFINITY;
    }
    for (int k = 0; k < KNN; ++k) {
        float best = INFINITY; int bj = -1;
        for (int j = 0; j < APG; ++j) {
            float v = d2s[t * 128 + (j ^ sw)];
            if (v < best || (bj < 0 && v == INFINITY)) { best = v; bj = j; }
        }
        d2s[t * 128 + (bj ^ sw)] = __int_as_float(0x7fc00000);  // NaN = consumed
        bool ev = (best < INFINITY);
        float d = ev ? __fsqrt_rn(best) : 1.0f;
        float cv = 0.0f;
        if (ev && d < 10.0f) cv = 0.5f * (cosf(d * 3.14159265f / 10.0f) + 1.0f);
        int e = (base + t) * KNN + k;
        dist[e]  = d;
        cvalp[e] = cv;
        if (cv > 0.0f) {
            int j = base + bj;
            int p = atomicAdd(&rev_cnt[j], 1);
            rev_e[(size_t)j * 128 + p] = e;
        }
    }
}

// ---------------------------------------------------------------------------
// K2: embedding gather
// ---------------------------------------------------------------------------
__global__ void embed_kernel(const int* __restrict__ z,
                             const float* __restrict__ emb,
                             float* __restrict__ h) {
    int i = blockIdx.x, t = threadIdx.x;
    h[(size_t)i * HID + t] = emb[(size_t)z[i] * HID + t];
}

// ---------------------------------------------------------------------------
// K3: dense MFMA GEMM, O[8192,128] = A[8192,128](fp32, split-bf16 hi+lo)
//     @ Bt^T + bias.  Bt stored [n][k] bf16. MODE 0: O = res (xj);
//     MODE 1: O += silu(res) (h update).
// 32 rows/block, 256 thr (4 waves, each 32 cols). ~52 KB LDS -> 3 blocks/CU.
// ---------------------------------------------------------------------------
template <int MODE>
__launch_bounds__(256)
__global__ void gemm_mfma(const float* __restrict__ A,
                          const u16* __restrict__ Bt,
                          const float* __restrict__ bias,
                          float* __restrict__ O) {
    __shared__ u16 s_ahi[32 * PAD128];
    __shared__ u16 s_alo[32 * PAD128];
    __shared__ u16 s_b[128 * PAD128];
    __shared__ float s_bias[128];
    int tid = threadIdx.x;
    int row0 = blockIdx.x * 32;
    {
        const float4* src = (const float4*)(A + (size_t)row0 * 128);
        for (int p = 0; p < 4; ++p) {
            int q = tid + p * 256;
            int r = q >> 5, k4 = (q & 31) * 4;
            float4 v = src[q];
            ushort4 hi, lo;
            hi.x = f2bf(v.x); lo.x = f2bf(v.x - bf2f(hi.x));
            hi.y = f2bf(v.y); lo.y = f2bf(v.y - bf2f(hi.y));
            hi.z = f2bf(v.z); lo.z = f2bf(v.z - bf2f(hi.z));
            hi.w = f2bf(v.w); lo.w = f2bf(v.w - bf2f(hi.w));
            *(ushort4*)&s_ahi[r * PAD128 + k4] = hi;
            *(ushort4*)&s_alo[r * PAD128 + k4] = lo;
        }
    }
    {
        const uint4* src = (const uint4*)Bt;
        for (int p = 0; p < 8; ++p) {
            int q = tid + p * 256;
            int r = q >> 4, c8 = (q & 15) * 8;
            *(uint4*)&s_b[r * PAD128 + c8] = src[q];
        }
    }
    if (tid < 128) s_bias[tid] = bias[tid];
    __syncthreads();

    int wv = tid >> 6, lane = tid & 63;
    int quad = lane >> 4, lr = lane & 15;
    int n0 = wv * 32;
    f32x4 acc[2][2];
#pragma unroll
    for (int mt = 0; mt < 2; ++mt)
#pragma unroll
        for (int nt = 0; nt < 2; ++nt) acc[mt][nt] = (f32x4){0.f, 0.f, 0.f, 0.f};
#pragma unroll
    for (int kk = 0; kk < 128; kk += 32) {
        bf16x8 ah0 = ldfrag(&s_ahi[(lr)      * PAD128 + kk + quad * 8]);
        bf16x8 ah1 = ldfrag(&s_ahi[(16 + lr) * PAD128 + kk + quad * 8]);
        bf16x8 al0 = ldfrag(&s_alo[(lr)      * PAD128 + kk + quad * 8]);
        bf16x8 al1 = ldfrag(&s_alo[(16 + lr) * PAD128 + kk + quad * 8]);
#pragma unroll
        for (int nt = 0; nt < 2; ++nt) {
            bf16x8 b = ldfrag(&s_b[(n0 + nt * 16 + lr) * PAD128 + kk + quad * 8]);
            acc[0][nt] = __builtin_amdgcn_mfma_f32_16x16x32_bf16(ah0, b, acc[0][nt], 0, 0, 0);
            acc[0][nt] = __builtin_amdgcn_mfma_f32_16x16x32_bf16(al0, b, acc[0][nt], 0, 0, 0);
            acc[1][nt] = __builtin_amdgcn_mfma_f32_16x16x32_bf16(ah1, b, acc[1][nt], 0, 0, 0);
            acc[1][nt] = __builtin_amdgcn_mfma_f32_16x16x32_bf16(al1, b, acc[1][nt], 0, 0, 0);
        }
    }
#pragma unroll
    for (int mt = 0; mt < 2; ++mt)
#pragma unroll
        for (int nt = 0; nt < 2; ++nt)
#pragma unroll
            for (int r = 0; r < 4; ++r) {
                int grow = row0 + mt * 16 + quad * 4 + r;
                int col = n0 + nt * 16 + lr;
                float v = acc[mt][nt][r] + s_bias[col];
                size_t off = (size_t)grow * 128 + col;
                if (MODE == 0) O[off] = v;
                else           O[off] += silu_f(v);
            }
}

// ---------------------------------------------------------------------------
// K4: W/msg producer. Block = 128 edges (4 centers). rbf computed in-LDS,
// Phase A (K=64 padded) and Phase B (K=128) via 16x16x32 bf16 MFMA.
// msg[e][f] = (t1@mw2 + b2) * cval[e] * xj[center(e)][f], stored bf16.
// ~110 KB LDS -> 1 block/CU.
// ---------------------------------------------------------------------------
__launch_bounds__(256)
__global__ void wcompute_kernel(const float* __restrict__ dist,
                                const float* __restrict__ cval,
                                const float* __restrict__ xj,
                                const u16* __restrict__ mw1t,   // [128][64]
                                const u16* __restrict__ mw2t,   // [128][128]
                                const float* __restrict__ b1,
                                const float* __restrict__ b2,
                                u16* __restrict__ msg) {        // [262144][128]
    __shared__ u16 s_rbf[128 * PAD64];
    __shared__ u16 s_w1[128 * PAD64];
    __shared__ u16 s_t1[128 * PAD128];
    __shared__ u16 s_w2[128 * PAD128];
    __shared__ float s_xj[4 * 128];
    __shared__ float s_cv[128];
    __shared__ float s_d[128];
    __shared__ float s_b1[128], s_b2[128];

    int tid = threadIdx.x;
    int eb0 = blockIdx.x * 128;
    {
        const uint4* src = (const uint4*)mw1t;
        for (int p = 0; p < 4; ++p) {
            int q = tid + p * 256;
            int r = q >> 3, c8 = (q & 7) * 8;
            *(uint4*)&s_w1[r * PAD64 + c8] = src[q];
        }
    }
    {
        const uint4* src = (const uint4*)mw2t;
        for (int p = 0; p < 8; ++p) {
            int q = tid + p * 256;
            int r = q >> 4, c8 = (q & 15) * 8;
            *(uint4*)&s_w2[r * PAD128 + c8] = src[q];
        }
    }
    if (tid < 128) {
        s_d[tid]  = dist[eb0 + tid];
        s_cv[tid] = cval[eb0 + tid];
        s_b1[tid] = b1[tid];
        s_b2[tid] = b2[tid];
        const float4* src = (const float4*)(xj + (size_t)(blockIdx.x * 4) * 128);
        ((float4*)s_xj)[tid] = src[tid];
    }
    __syncthreads();

    // rbf tile: 128 edges x 64 gaussians (50 real, rest 0)
    const float wgi = 49.0f / 10.0f;           // 1/width
    for (int p = 0; p < 32; ++p) {
        int q = tid + p * 256;                 // 0..8191
        int row = q >> 6, g = q & 63;
        float v = 0.0f;
        if (g < 50) {
            float tt = (s_d[row] - (10.0f / 49.0f) * (float)g) * wgi;
            v = expf(-0.5f * tt * tt);
        }
        s_rbf[row * PAD64 + g] = f2bf(v);
    }
    __syncthreads();

    int wv = tid >> 6, lane = tid & 63;
    int quad = lane >> 4, lr = lane & 15;
    int m0 = wv * 32;

    // Phase A: t1 = silu(rbf @ mw1 + b1)
    {
        f32x4 accA[2][8];
#pragma unroll
        for (int mt = 0; mt < 2; ++mt)
#pragma unroll
            for (int nt = 0; nt < 8; ++nt) accA[mt][nt] = (f32x4){0.f, 0.f, 0.f, 0.f};
#pragma unroll
        for (int kk = 0; kk < 64; kk += 32) {
            bf16x8 a0 = ldfrag(&s_rbf[(m0 + lr)      * PAD64 + kk + quad * 8]);
            bf16x8 a1 = ldfrag(&s_rbf[(m0 + 16 + lr) * PAD64 + kk + quad * 8]);
#pragma unroll
            for (int nt = 0; nt < 8; ++nt) {
                bf16x8 b = ldfrag(&s_w1[(nt * 16 + lr) * PAD64 + kk + quad * 8]);
                accA[0][nt] = __builtin_amdgcn_mfma_f32_16x16x32_bf16(a0, b, accA[0][nt], 0, 0, 0);
                accA[1][nt] = __builtin_amdgcn_mfma_f32_16x16x32_bf16(a1, b, accA[1][nt], 0, 0, 0);
            }
        }
#pragma unroll
        for (int mt = 0; mt < 2; ++mt)
#pragma unroll
            for (int nt = 0; nt < 8; ++nt)
#pragma unroll
                for (int r = 0; r < 4; ++r) {
                    int row = m0 + mt * 16 + quad * 4 + r;
                    int col = nt * 16 + lr;
                    float v = accA[mt][nt][r] + s_b1[col];
                    s_t1[row * PAD128 + col] = f2bf(silu_f(v));
                }
    }
    __syncthreads();

    // Phase B: msg = (t1 @ mw2 + b2) * cv * xj
    {
        f32x4 accB[2][8];
#pragma unroll
        for (int mt = 0; mt < 2; ++mt)
#pragma unroll
            for (int nt = 0; nt < 8; ++nt) accB[mt][nt] = (f32x4){0.f, 0.f, 0.f, 0.f};
#pragma unroll
        for (int kk = 0; kk < 128; kk += 32) {
            bf16x8 a0 = ldfrag(&s_t1[(m0 + lr)      * PAD128 + kk + quad * 8]);
            bf16x8 a1 = ldfrag(&s_t1[(m0 + 16 + lr) * PAD128 + kk + quad * 8]);
#pragma unroll
            for (int nt = 0; nt < 8; ++nt) {
                bf16x8 b = ldfrag(&s_w2[(nt * 16 + lr) * PAD128 + kk + quad * 8]);
                accB[0][nt] = __builtin_amdgcn_mfma_f32_16x16x32_bf16(a0, b, accB[0][nt], 0, 0, 0);
                accB[1][nt] = __builtin_amdgcn_mfma_f32_16x16x32_bf16(a1, b, accB[1][nt], 0, 0, 0);
            }
        }
#pragma unroll
        for (int mt = 0; mt < 2; ++mt)
#pragma unroll
            for (int nt = 0; nt < 8; ++nt)
#pragma unroll
                for (int r = 0; r < 4; ++r) {
                    int row = m0 + mt * 16 + quad * 4 + r;
                    int col = nt * 16 + lr;
                    float v = (accB[mt][nt][r] + s_b2[col]) * s_cv[row]
                              * s_xj[(row >> 5) * 128 + col];
                    msg[(size_t)(eb0 + row) * 128 + col] = f2bf(v);
                }
    }
}

// ---------------------------------------------------------------------------
// K5: gather — agg[j] = sum over incoming edges of msg[e]. No atomics.
// One wave per receiver, lane handles 2 features.
// ---------------------------------------------------------------------------
__launch_bounds__(256)
__global__ void gather_kernel(const int* __restrict__ rev_cnt,
                              const int* __restrict__ rev_e,
                              const u16* __restrict__ msg,
                              float* __restrict__ agg) {
    int j = blockIdx.x * 4 + (threadIdx.x >> 6);
    int lane = threadIdx.x & 63;
    int deg = rev_cnt[j];
    const int* lst = rev_e + (size_t)j * 128;
    float a0 = 0.f, a1 = 0.f;
    for (int it = 0; it < deg; ++it) {
        int e = lst[it];
        ushort2 m = *(const ushort2*)(msg + (size_t)e * 128 + lane * 2);
        a0 += bf2f(m.x);
        a1 += bf2f(m.y);
    }
    float2 r; r.x = a0; r.y = a1;
    *(float2*)(agg + (size_t)j * 128 + lane * 2) = r;
}

// ---------------------------------------------------------------------------
// K6: output head + finalize
// ---------------------------------------------------------------------------
__launch_bounds__(64)
__global__ void head_kernel(const float* __restrict__ h,
                            const float* __restrict__ ow1,
                            const float* __restrict__ ob1,
                            const float* __restrict__ ow2,
                            const float* __restrict__ ob2,
                            float* __restrict__ gsum) {
    int i = blockIdx.x;
    int c = threadIdx.x;
    const float* hrow = h + (size_t)i * 128;
    float o = ob1[c];
    for (int f = 0; f < 128; ++f) o += hrow[f] * ow1[f * 64 + c];
    o = silu_f(o);
    float v = o * ow2[c];
    for (int off = 32; off > 0; off >>= 1) v += __shfl_down(v, off, 64);
    if (c == 0) {
        int g = i >> 7;
        atomicAdd(&gsum[g], v + ob2[0]);
    }
}

__global__ void finalize_kernel(const float* __restrict__ gsum, void* __restrict__ out,
                                const int* __restrict__ flag) {
    int t = threadIdx.x;
    if (*flag) ((float*)out)[t] = gsum[t];
    else       ((u16*)out)[t]   = f2bf(gsum[t]);
}

// ---------------------------------------------------------------------------
extern "C" void kernel_launch(void* const* d_in, const int* in_sizes, int n_in,
                              void* d_out, int out_size, void* d_ws, size_t ws_size,
                              hipStream_t stream) {
    const void* pos  = d_in[0];
    const int*  z    = (const int*)d_in[1];
    // d_in[2] = batch (implicit: graph = i >> 7)
    const void* emb  = d_in[3];
    const void* mw1  = d_in[4];
    const void* mb1  = d_in[5];
    const void* mw2  = d_in[6];
    const void* mb2  = d_in[7];
    const void* l1w  = d_in[8];
    const void* l1b  = d_in[9];
    const void* l2w  = d_in[10];
    const void* l2b  = d_in[11];
    const void* ow1  = d_in[12];
    const void* ob1  = d_in[13];
    const void* ow2  = d_in[14];
    const void* ob2  = d_in[15];

    char* ws = (char*)d_ws;
    const size_t KB = 1024, MB = 1048576;
    int*   w_flag  = (int*)  (ws);
    float* c_pos   = (float*)(ws + 4   * KB);
    float* c_emb   = (float*)(ws + 112 * KB);
    float* c_mb1   = (float*)(ws + 168 * KB);
    float* c_mb2   = (float*)(ws + 172 * KB);
    float* c_l1b   = (float*)(ws + 176 * KB);
    float* c_l2b   = (float*)(ws + 180 * KB);
    float* c_ow1   = (float*)(ws + 184 * KB);
    float* c_ob1   = (float*)(ws + 220 * KB);
    float* c_ow2   = (float*)(ws + 221 * KB);
    float* c_ob2   = (float*)(ws + 222 * KB);
    float* w_gsum  = (float*)(ws + 224 * KB);
    u16*   c_l1wt  = (u16*)  (ws + 256 * KB);
    u16*   c_l2wt  = (u16*)  (ws + 448 * KB);
    u16*   c_mw2t  = (u16*)  (ws + 640 * KB);
    u16*   c_mw1t  = (u16*)  (ws + 832 * KB);
    float* w_dist  = (float*)(ws + 1  * MB);
    float* w_cval  = (float*)(ws + 2  * MB);
    int*   rev_cnt = (int*)  (ws + 3  * MB);
    int*   rev_e   = (int*)  (ws + 4  * MB);
    float* w_h     = (float*)(ws + 8  * MB);
    float* w_xj    = (float*)(ws + 12 * MB);
    float* w_agg   = (float*)(ws + 16 * MB);
    u16*   w_msg   = (u16*)  (ws + 20 * MB);   // 64 MB

    hipMemsetAsync(rev_cnt, 0, NATOMS * sizeof(int), stream);
    hipMemsetAsync(w_gsum, 0, GRAPHS * sizeof(float), stream);

    probe_kernel<<<1, 256, 0, stream>>>((const u16*)emb, w_flag);

    IngestDesc dsc;
    const void* srcs[NARR] = {pos, emb, mb1, mb2, l1b, l2b, ow1, ob1, ow2, ob2};
    void* dsts[NARR] = {c_pos, c_emb, c_mb1, c_mb2, c_l1b, c_l2b, c_ow1, c_ob1,
                        c_ow2, c_ob2};
    int ns[NARR] = {24576, 12800, 768, 768, 768, 768, 8192, 64, 64, 1};
    int total = 0;
    for (int a = 0; a < NARR; ++a) {
        dsc.src[a] = srcs[a]; dsc.dst[a] = dsts[a]; dsc.n[a] = ns[a];
        total += ns[a];
    }
    ingest_kernel<<<(total + 255) / 256, 256, 0, stream>>>(dsc, w_flag, total);
    prep_weights<<<1344, 256, 0, stream>>>(l1w, l2w, mw2, mw1,
                                           c_l1wt, c_l2wt, c_mw2t, c_mw1t, w_flag);

    build_graph_kernel<<<GRAPHS, APG, 0, stream>>>(c_pos, w_dist, w_cval,
                                                   rev_cnt, rev_e);
    embed_kernel<<<NATOMS, HID, 0, stream>>>(z, c_emb, w_h);

    for (int l = 0; l < LAYERS; ++l) {
        gemm_mfma<0><<<NATOMS / 32, 256, 0, stream>>>(
            w_h, c_l1wt + (size_t)l * 16384, c_l1b + (size_t)l * 128, w_xj);
        wcompute_kernel<<<NATOMS * KNN / 128, 256, 0, stream>>>(
            w_dist, w_cval, w_xj,
            c_mw1t + (size_t)l * 8192, c_mw2t + (size_t)l * 16384,
            c_mb1 + (size_t)l * 128, c_mb2 + (size_t)l * 128, w_msg);
        gather_kernel<<<NATOMS / 4, 256, 0, stream>>>(rev_cnt, rev_e, w_msg, w_agg);
        gemm_mfma<1><<<NATOMS / 32, 256, 0, stream>>>(
            w_agg, c_l2wt + (size_t)l * 16384, c_l2b + (size_t)l * 128, w_h);
    }

    head_kernel<<<NATOMS, 64, 0, stream>>>(w_h, c_ow1, c_ob1, c_ow2, c_ob2, w_gsum);
    finalize_kernel<<<1, GRAPHS, 0, stream>>>(w_gsum, (void*)d_out, w_flag);
}

// Round 4
// 904.820 us; speedup vs baseline: 4.2041x; 1.5237x over previous
//
#include <hip/hip_runtime.h>
#include <math.h>

typedef unsigned short u16;
typedef unsigned int   u32;
typedef unsigned long long u64;

#define NATOMS 8192
#define GRAPHS 64
#define APG    128
#define KNN    32
#define NGAUSS 50
#define HID    128
#define LAYERS 6
#define PAD128 136

typedef __attribute__((ext_vector_type(8))) short bf16x8;
typedef __attribute__((ext_vector_type(4))) float f32x4;

__device__ __forceinline__ float bf2f(u16 v) {
    return __uint_as_float(((u32)v) << 16);
}
__device__ __forceinline__ u16 f2bf(float f) {
    u32 u = __float_as_uint(f);
    u32 lsb = (u >> 16) & 1u;
    u += 0x7fffu + lsb;
    return (u16)(u >> 16);
}
__device__ __forceinline__ float silu_f(float x) {
    float s = 1.0f / (1.0f + expf(-x));
    return x * s;
}
__device__ __forceinline__ bf16x8 ldfrag(const u16* p) {
    return *(const bf16x8*)__builtin_assume_aligned(p, 16);
}
__device__ __forceinline__ u64 shfl_xor_u64(u64 v, int mask) {
    u32 lo = (u32)v, hi = (u32)(v >> 32);
    lo = (u32)__shfl_xor((int)lo, mask, 64);
    hi = (u32)__shfl_xor((int)hi, mask, 64);
    return ((u64)hi << 32) | lo;
}

// ---------------------------------------------------------------------------
// K0: dtype probe. Even u16 half-words of emb: real bf16 weights if buffer is
// bf16 (|x| small), random fp32 mantissa words if fp32 (huge/NaN p~0.46 each).
// ---------------------------------------------------------------------------
__global__ void probe_kernel(const u16* __restrict__ raw, int* __restrict__ flag) {
    __shared__ int s;
    int t = threadIdx.x;
    if (t == 0) s = 0;
    __syncthreads();
    float x = bf2f(raw[2 * t]);
    if (!(fabsf(x) < 1000.0f)) atomicOr(&s, 1);
    __syncthreads();
    if (t == 0) *flag = s;
}

// ---------------------------------------------------------------------------
// K0b: ingest small fp32-canonical arrays.
// ---------------------------------------------------------------------------
#define NARR 10
struct IngestDesc {
    const void* src[NARR];
    void*       dst[NARR];
    int         n[NARR];
};

__global__ void ingest_kernel(IngestDesc d, const int* __restrict__ flag, int total) {
    int gid = blockIdx.x * blockDim.x + threadIdx.x;
    if (gid >= total) return;
    int a = 0, off = gid;
    while (off >= d.n[a]) { off -= d.n[a]; ++a; }
    bool f32in = (*flag != 0);
    float v = f32in ? ((const float*)d.src[a])[off]
                    : bf2f(((const u16*)d.src[a])[off]);
    ((float*)d.dst[a])[off] = v;
}

// ---------------------------------------------------------------------------
// K0c: weight prep — transpose to [n][k] bf16 for MFMA B-operands.
// l1wt/l2wt/mw2t: [6][128][128]; mw1t: [6][128][64] with k in [50,64) zeroed.
// ---------------------------------------------------------------------------
__global__ void prep_weights(const void* __restrict__ l1w, const void* __restrict__ l2w,
                             const void* __restrict__ mw2, const void* __restrict__ mw1,
                             u16* __restrict__ l1wt, u16* __restrict__ l2wt,
                             u16* __restrict__ mw2t, u16* __restrict__ mw1t,
                             const int* __restrict__ flag) {
    int gid = blockIdx.x * blockDim.x + threadIdx.x;
    bool f32in = (*flag != 0);
    if (gid < 3 * 98304) {
        int seg = gid / 98304;
        int t = gid % 98304;
        int l = t >> 14;
        int n = (t >> 7) & 127;
        int k = t & 127;
        const void* src = (seg == 0) ? l1w : ((seg == 1) ? l2w : mw2);
        u16* dst = (seg == 0) ? l1wt : ((seg == 1) ? l2wt : mw2t);
        int si = l * 16384 + k * 128 + n;
        float v = f32in ? ((const float*)src)[si] : bf2f(((const u16*)src)[si]);
        dst[t] = f2bf(v);
    } else {
        int t = gid - 3 * 98304;
        if (t < 49152) {
            int l = t >> 13;
            int n = (t >> 6) & 127;
            int k = t & 63;
            float v = 0.0f;
            if (k < 50) {
                int si = l * 6400 + k * 128 + n;
                v = f32in ? ((const float*)mw1)[si] : bf2f(((const u16*)mw1)[si]);
            }
            mw1t[t] = f2bf(v);
        }
    }
}

// ---------------------------------------------------------------------------
// K1: graph build, one WAVE per center atom (4 waves/block, 2048 blocks).
// Lane holds candidates j=lane, j=lane+64 packed as (d2_bits<<32)|j — u64
// min == lexicographic (d2, j), exactly jax.lax.top_k tie order. 32 rounds
// of shfl_xor butterfly min; owner lane writes dist/cval + rev adjacency.
// ---------------------------------------------------------------------------
__launch_bounds__(256)
__global__ void build_graph_kernel(const float* __restrict__ pos,
                                   float* __restrict__ dist,
                                   float* __restrict__ cvalp,
                                   int* __restrict__ rev_cnt,
                                   int* __restrict__ rev_e) {
    int wv = threadIdx.x >> 6, lane = threadIdx.x & 63;
    int t = blockIdx.x * 4 + wv;           // global center atom id
    int tl = t & 127;                      // index within graph
    int base = t & ~127;                   // graph base
    float cx = pos[t * 3 + 0];
    float cy = pos[t * 3 + 1];
    float cz = pos[t * 3 + 2];
    u64 key[2];
#pragma unroll
    for (int c = 0; c < 2; ++c) {
        int j = lane + c * 64;
        float jx = pos[(base + j) * 3 + 0];
        float jy = pos[(base + j) * 3 + 1];
        float jz = pos[(base + j) * 3 + 2];
        float dx = __fsub_rn(cx, jx);
        float dy = __fsub_rn(cy, jy);
        float dz = __fsub_rn(cz, jz);
        float d2 = __fadd_rn(__fadd_rn(__fmul_rn(dx, dx), __fmul_rn(dy, dy)),
                             __fmul_rn(dz, dz));
        bool valid = (j != tl) && (d2 < 100.0f);
        key[c] = valid ? ((((u64)__float_as_uint(d2)) << 32) | (u32)j) : ~0ULL;
    }
    for (int k = 0; k < KNN; ++k) {
        u64 m = key[0] < key[1] ? key[0] : key[1];
#pragma unroll
        for (int off = 32; off > 0; off >>= 1) {
            u64 o = shfl_xor_u64(m, off);
            if (o < m) m = o;
        }
        int e = t * KNN + k;
        if (m == ~0ULL) {
            if (lane == 0) { dist[e] = 1.0f; cvalp[e] = 0.0f; }
        } else {
            if (key[0] == m) key[0] = ~0ULL;
            if (key[1] == m) key[1] = ~0ULL;
            if (lane == (int)(m & 63)) {
                float d2 = __uint_as_float((u32)(m >> 32));
                float d = __fsqrt_rn(d2);
                float cv = (d < 10.0f) ? 0.5f * (cosf(d * 3.14159265f / 10.0f) + 1.0f)
                                       : 0.0f;
                dist[e] = d;
                cvalp[e] = cv;
                int j = base + (int)(m & 0xffffffffu);
                int p = atomicAdd(&rev_cnt[j], 1);
                rev_e[(size_t)j * 128 + p] = e;
            }
        }
    }
}

// ---------------------------------------------------------------------------
// K2: embedding gather
// ---------------------------------------------------------------------------
__global__ void embed_kernel(const int* __restrict__ z,
                             const float* __restrict__ emb,
                             float* __restrict__ h) {
    int i = blockIdx.x, t = threadIdx.x;
    h[(size_t)i * HID + t] = emb[(size_t)z[i] * HID + t];
}

// ---------------------------------------------------------------------------
// K3: dense MFMA GEMM, O[8192,128] = A[8192,128](fp32, split-bf16 hi+lo)
//     @ Bt^T + bias.  Bt stored [n][k] bf16. MODE 0: O = res (xj);
//     MODE 1: O += silu(res) (h update).
// ---------------------------------------------------------------------------
template <int MODE>
__launch_bounds__(256)
__global__ void gemm_mfma(const float* __restrict__ A,
                          const u16* __restrict__ Bt,
                          const float* __restrict__ bias,
                          float* __restrict__ O) {
    __shared__ u16 s_ahi[32 * PAD128];
    __shared__ u16 s_alo[32 * PAD128];
    __shared__ u16 s_b[128 * PAD128];
    __shared__ float s_bias[128];
    int tid = threadIdx.x;
    int row0 = blockIdx.x * 32;
    {
        const float4* src = (const float4*)(A + (size_t)row0 * 128);
        for (int p = 0; p < 4; ++p) {
            int q = tid + p * 256;
            int r = q >> 5, k4 = (q & 31) * 4;
            float4 v = src[q];
            ushort4 hi, lo;
            hi.x = f2bf(v.x); lo.x = f2bf(v.x - bf2f(hi.x));
            hi.y = f2bf(v.y); lo.y = f2bf(v.y - bf2f(hi.y));
            hi.z = f2bf(v.z); lo.z = f2bf(v.z - bf2f(hi.z));
            hi.w = f2bf(v.w); lo.w = f2bf(v.w - bf2f(hi.w));
            *(ushort4*)&s_ahi[r * PAD128 + k4] = hi;
            *(ushort4*)&s_alo[r * PAD128 + k4] = lo;
        }
    }
    {
        const uint4* src = (const uint4*)Bt;
        for (int p = 0; p < 8; ++p) {
            int q = tid + p * 256;
            int r = q >> 4, c8 = (q & 15) * 8;
            *(uint4*)&s_b[r * PAD128 + c8] = src[q];
        }
    }
    if (tid < 128) s_bias[tid] = bias[tid];
    __syncthreads();

    int wv = tid >> 6, lane = tid & 63;
    int quad = lane >> 4, lr = lane & 15;
    int n0 = wv * 32;
    f32x4 acc[2][2];
#pragma unroll
    for (int mt = 0; mt < 2; ++mt)
#pragma unroll
        for (int nt = 0; nt < 2; ++nt) acc[mt][nt] = (f32x4){0.f, 0.f, 0.f, 0.f};
#pragma unroll
    for (int kk = 0; kk < 128; kk += 32) {
        bf16x8 ah0 = ldfrag(&s_ahi[(lr)      * PAD128 + kk + quad * 8]);
        bf16x8 ah1 = ldfrag(&s_ahi[(16 + lr) * PAD128 + kk + quad * 8]);
        bf16x8 al0 = ldfrag(&s_alo[(lr)      * PAD128 + kk + quad * 8]);
        bf16x8 al1 = ldfrag(&s_alo[(16 + lr) * PAD128 + kk + quad * 8]);
#pragma unroll
        for (int nt = 0; nt < 2; ++nt) {
            bf16x8 b = ldfrag(&s_b[(n0 + nt * 16 + lr) * PAD128 + kk + quad * 8]);
            acc[0][nt] = __builtin_amdgcn_mfma_f32_16x16x32_bf16(ah0, b, acc[0][nt], 0, 0, 0);
            acc[0][nt] = __builtin_amdgcn_mfma_f32_16x16x32_bf16(al0, b, acc[0][nt], 0, 0, 0);
            acc[1][nt] = __builtin_amdgcn_mfma_f32_16x16x32_bf16(ah1, b, acc[1][nt], 0, 0, 0);
            acc[1][nt] = __builtin_amdgcn_mfma_f32_16x16x32_bf16(al1, b, acc[1][nt], 0, 0, 0);
        }
    }
#pragma unroll
    for (int mt = 0; mt < 2; ++mt)
#pragma unroll
        for (int nt = 0; nt < 2; ++nt)
#pragma unroll
            for (int r = 0; r < 4; ++r) {
                int grow = row0 + mt * 16 + quad * 4 + r;
                int col = n0 + nt * 16 + lr;
                float v = acc[mt][nt][r] + s_bias[col];
                size_t off = (size_t)grow * 128 + col;
                if (MODE == 0) O[off] = v;
                else           O[off] += silu_f(v);
            }
}

// ---------------------------------------------------------------------------
// K4: W/msg producer. Block = 128 edges (4 centers). rbf A-fragments computed
// directly in registers (no LDS); w1/w2 B-fragments loaded from global
// (L2-hot, 16B/lane aligned). Only LDS: t1 C->A layout transpose (~38 KB).
// msg[e][f] = (silu(rbf@mw1+b1)@mw2 + b2) * cval[e] * xj[center(e)][f], bf16.
// ---------------------------------------------------------------------------
__launch_bounds__(256)
__global__ void wcompute_kernel(const float* __restrict__ dist,
                                const float* __restrict__ cval,
                                const float* __restrict__ xj,
                                const u16* __restrict__ mw1t,   // [128][64]
                                const u16* __restrict__ mw2t,   // [128][128]
                                const float* __restrict__ b1,
                                const float* __restrict__ b2,
                                u16* __restrict__ msg) {        // [262144][128]
    __shared__ u16 s_t1[128 * PAD128];     // 34.8 KB
    __shared__ float s_xj[4 * 128];
    __shared__ float s_cv[128];
    __shared__ float s_d[128];
    __shared__ float s_b1[128], s_b2[128];

    int tid = threadIdx.x;
    int eb0 = blockIdx.x * 128;
    if (tid < 128) {
        s_d[tid]  = dist[eb0 + tid];
        s_cv[tid] = cval[eb0 + tid];
        s_b1[tid] = b1[tid];
        s_b2[tid] = b2[tid];
        const float4* src = (const float4*)(xj + (size_t)(blockIdx.x * 4) * 128);
        ((float4*)s_xj)[tid] = src[tid];
    }
    __syncthreads();

    int wv = tid >> 6, lane = tid & 63;
    int quad = lane >> 4, lr = lane & 15;
    int m0 = wv * 32;

    // Phase A: t1 = silu(rbf @ mw1 + b1), rbf computed per-lane in registers
    {
        const float wg = 10.0f / 49.0f, wgi = 49.0f / 10.0f;
        bf16x8 afr[2][2];                  // [mt][kk]
#pragma unroll
        for (int mt = 0; mt < 2; ++mt) {
            float d = s_d[m0 + mt * 16 + lr];
#pragma unroll
            for (int kki = 0; kki < 2; ++kki) {
#pragma unroll
                for (int j = 0; j < 8; ++j) {
                    int k = kki * 32 + quad * 8 + j;
                    float v = 0.0f;
                    if (k < 50) {
                        float tt = (d - wg * (float)k) * wgi;
                        v = expf(-0.5f * tt * tt);
                    }
                    afr[mt][kki][j] = (short)f2bf(v);
                }
            }
        }
        f32x4 accA[2][8];
#pragma unroll
        for (int mt = 0; mt < 2; ++mt)
#pragma unroll
            for (int nt = 0; nt < 8; ++nt) accA[mt][nt] = (f32x4){0.f, 0.f, 0.f, 0.f};
#pragma unroll
        for (int kki = 0; kki < 2; ++kki) {
#pragma unroll
            for (int nt = 0; nt < 8; ++nt) {
                bf16x8 b = ldfrag(mw1t + (nt * 16 + lr) * 64 + kki * 32 + quad * 8);
                accA[0][nt] = __builtin_amdgcn_mfma_f32_16x16x32_bf16(afr[0][kki], b, accA[0][nt], 0, 0, 0);
                accA[1][nt] = __builtin_amdgcn_mfma_f32_16x16x32_bf16(afr[1][kki], b, accA[1][nt], 0, 0, 0);
            }
        }
#pragma unroll
        for (int mt = 0; mt < 2; ++mt)
#pragma unroll
            for (int nt = 0; nt < 8; ++nt)
#pragma unroll
                for (int r = 0; r < 4; ++r) {
                    int row = m0 + mt * 16 + quad * 4 + r;
                    int col = nt * 16 + lr;
                    float v = accA[mt][nt][r] + s_b1[col];
                    s_t1[row * PAD128 + col] = f2bf(silu_f(v));
                }
    }
    __syncthreads();

    // Phase B: msg = (t1 @ mw2 + b2) * cv * xj
    {
        f32x4 accB[2][8];
#pragma unroll
        for (int mt = 0; mt < 2; ++mt)
#pragma unroll
            for (int nt = 0; nt < 8; ++nt) accB[mt][nt] = (f32x4){0.f, 0.f, 0.f, 0.f};
#pragma unroll
        for (int kk = 0; kk < 128; kk += 32) {
            bf16x8 a0 = ldfrag(&s_t1[(m0 + lr)      * PAD128 + kk + quad * 8]);
            bf16x8 a1 = ldfrag(&s_t1[(m0 + 16 + lr) * PAD128 + kk + quad * 8]);
#pragma unroll
            for (int nt = 0; nt < 8; ++nt) {
                bf16x8 b = ldfrag(mw2t + (nt * 16 + lr) * 128 + kk + quad * 8);
                accB[0][nt] = __builtin_amdgcn_mfma_f32_16x16x32_bf16(a0, b, accB[0][nt], 0, 0, 0);
                accB[1][nt] = __builtin_amdgcn_mfma_f32_16x16x32_bf16(a1, b, accB[1][nt], 0, 0, 0);
            }
        }
#pragma unroll
        for (int mt = 0; mt < 2; ++mt)
#pragma unroll
            for (int nt = 0; nt < 8; ++nt)
#pragma unroll
                for (int r = 0; r < 4; ++r) {
                    int row = m0 + mt * 16 + quad * 4 + r;
                    int col = nt * 16 + lr;
                    float v = (accB[mt][nt][r] + s_b2[col]) * s_cv[row]
                              * s_xj[wv * 128 + col];
                    msg[(size_t)(eb0 + row) * 128 + col] = f2bf(v);
                }
    }
}

// ---------------------------------------------------------------------------
// K5: gather — agg[j] = sum over incoming edges of msg[e]. No atomics.
// ---------------------------------------------------------------------------
__launch_bounds__(256)
__global__ void gather_kernel(const int* __restrict__ rev_cnt,
                              const int* __restrict__ rev_e,
                              const u16* __restrict__ msg,
                              float* __restrict__ agg) {
    int j = blockIdx.x * 4 + (threadIdx.x >> 6);
    int lane = threadIdx.x & 63;
    int deg = rev_cnt[j];
    const int* lst = rev_e + (size_t)j * 128;
    float a0 = 0.f, a1 = 0.f;
    for (int it = 0; it < deg; ++it) {
        int e = lst[it];
        ushort2 m = *(const ushort2*)(msg + (size_t)e * 128 + lane * 2);
        a0 += bf2f(m.x);
        a1 += bf2f(m.y);
    }
    float2 r; r.x = a0; r.y = a1;
    *(float2*)(agg + (size_t)j * 128 + lane * 2) = r;
}

// ---------------------------------------------------------------------------
// K6: output head + finalize
// ---------------------------------------------------------------------------
__launch_bounds__(64)
__global__ void head_kernel(const float* __restrict__ h,
                            const float* __restrict__ ow1,
                            const float* __restrict__ ob1,
                            const float* __restrict__ ow2,
                            const float* __restrict__ ob2,
                            float* __restrict__ gsum) {
    int i = blockIdx.x;
    int c = threadIdx.x;
    const float* hrow = h + (size_t)i * 128;
    float o = ob1[c];
    for (int f = 0; f < 128; ++f) o += hrow[f] * ow1[f * 64 + c];
    o = silu_f(o);
    float v = o * ow2[c];
    for (int off = 32; off > 0; off >>= 1) v += __shfl_down(v, off, 64);
    if (c == 0) {
        int g = i >> 7;
        atomicAdd(&gsum[g], v + ob2[0]);
    }
}

__global__ void finalize_kernel(const float* __restrict__ gsum, void* __restrict__ out,
                                const int* __restrict__ flag) {
    int t = threadIdx.x;
    if (*flag) ((float*)out)[t] = gsum[t];
    else       ((u16*)out)[t]   = f2bf(gsum[t]);
}

// ---------------------------------------------------------------------------
extern "C" void kernel_launch(void* const* d_in, const int* in_sizes, int n_in,
                              void* d_out, int out_size, void* d_ws, size_t ws_size,
                              hipStream_t stream) {
    const void* pos  = d_in[0];
    const int*  z    = (const int*)d_in[1];
    // d_in[2] = batch (implicit: graph = i >> 7)
    const void* emb  = d_in[3];
    const void* mw1  = d_in[4];
    const void* mb1  = d_in[5];
    const void* mw2  = d_in[6];
    const void* mb2  = d_in[7];
    const void* l1w  = d_in[8];
    const void* l1b  = d_in[9];
    const void* l2w  = d_in[10];
    const void* l2b  = d_in[11];
    const void* ow1  = d_in[12];
    const void* ob1  = d_in[13];
    const void* ow2  = d_in[14];
    const void* ob2  = d_in[15];

    char* ws = (char*)d_ws;
    const size_t KB = 1024, MB = 1048576;
    int*   w_flag  = (int*)  (ws);
    float* c_pos   = (float*)(ws + 4   * KB);
    float* c_emb   = (float*)(ws + 112 * KB);
    float* c_mb1   = (float*)(ws + 168 * KB);
    float* c_mb2   = (float*)(ws + 172 * KB);
    float* c_l1b   = (float*)(ws + 176 * KB);
    float* c_l2b   = (float*)(ws + 180 * KB);
    float* c_ow1   = (float*)(ws + 184 * KB);
    float* c_ob1   = (float*)(ws + 220 * KB);
    float* c_ow2   = (float*)(ws + 221 * KB);
    float* c_ob2   = (float*)(ws + 222 * KB);
    float* w_gsum  = (float*)(ws + 224 * KB);
    u16*   c_l1wt  = (u16*)  (ws + 256 * KB);
    u16*   c_l2wt  = (u16*)  (ws + 448 * KB);
    u16*   c_mw2t  = (u16*)  (ws + 640 * KB);
    u16*   c_mw1t  = (u16*)  (ws + 832 * KB);
    float* w_dist  = (float*)(ws + 1  * MB);
    float* w_cval  = (float*)(ws + 2  * MB);
    int*   rev_cnt = (int*)  (ws + 3  * MB);
    int*   rev_e   = (int*)  (ws + 4  * MB);
    float* w_h     = (float*)(ws + 8  * MB);
    float* w_xj    = (float*)(ws + 12 * MB);
    float* w_agg   = (float*)(ws + 16 * MB);
    u16*   w_msg   = (u16*)  (ws + 20 * MB);   // 64 MB

    hipMemsetAsync(rev_cnt, 0, NATOMS * sizeof(int), stream);
    hipMemsetAsync(w_gsum, 0, GRAPHS * sizeof(float), stream);

    probe_kernel<<<1, 256, 0, stream>>>((const u16*)emb, w_flag);

    IngestDesc dsc;
    const void* srcs[NARR] = {pos, emb, mb1, mb2, l1b, l2b, ow1, ob1, ow2, ob2};
    void* dsts[NARR] = {c_pos, c_emb, c_mb1, c_mb2, c_l1b, c_l2b, c_ow1, c_ob1,
                        c_ow2, c_ob2};
    int ns[NARR] = {24576, 12800, 768, 768, 768, 768, 8192, 64, 64, 1};
    int total = 0;
    for (int a = 0; a < NARR; ++a) {
        dsc.src[a] = srcs[a]; dsc.dst[a] = dsts[a]; dsc.n[a] = ns[a];
        total += ns[a];
    }
    ingest_kernel<<<(total + 255) / 256, 256, 0, stream>>>(dsc, w_flag, total);
    prep_weights<<<1344, 256, 0, stream>>>(l1w, l2w, mw2, mw1,
                                           c_l1wt, c_l2wt, c_mw2t, c_mw1t, w_flag);

    build_graph_kernel<<<NATOMS / 4, 256, 0, stream>>>(c_pos, w_dist, w_cval,
                                                       rev_cnt, rev_e);
    embed_kernel<<<NATOMS, HID, 0, stream>>>(z, c_emb, w_h);

    for (int l = 0; l < LAYERS; ++l) {
        gemm_mfma<0><<<NATOMS / 32, 256, 0, stream>>>(
            w_h, c_l1wt + (size_t)l * 16384, c_l1b + (size_t)l * 128, w_xj);
        wcompute_kernel<<<NATOMS * KNN / 128, 256, 0, stream>>>(
            w_dist, w_cval, w_xj,
            c_mw1t + (size_t)l * 8192, c_mw2t + (size_t)l * 16384,
            c_mb1 + (size_t)l * 128, c_mb2 + (size_t)l * 128, w_msg);
        gather_kernel<<<NATOMS / 4, 256, 0, stream>>>(rev_cnt, rev_e, w_msg, w_agg);
        gemm_mfma<1><<<NATOMS / 32, 256, 0, stream>>>(
            w_agg, c_l2wt + (size_t)l * 16384, c_l2b + (size_t)l * 128, w_h);
    }

    head_kernel<<<NATOMS, 64, 0, stream>>>(w_h, c_ow1, c_ob1, c_ow2, c_ob2, w_gsum);
    finalize_kernel<<<1, GRAPHS, 0, stream>>>(w_gsum, (void*)d_out, w_flag);
}

// Round 5
// 704.818 us; speedup vs baseline: 5.3971x; 1.2838x over previous
//
#include <hip/hip_runtime.h>
#include <math.h>

typedef unsigned short u16;
typedef unsigned int   u32;
typedef unsigned long long u64;

#define NATOMS 8192
#define GRAPHS 64
#define APG    128
#define KNN    32
#define NGAUSS 50
#define HID    128
#define LAYERS 6
#define PAD128 136

typedef __attribute__((ext_vector_type(8))) short bf16x8;
typedef __attribute__((ext_vector_type(4))) float f32x4;

__device__ __forceinline__ float bf2f(u16 v) {
    return __uint_as_float(((u32)v) << 16);
}
__device__ __forceinline__ u16 f2bf(float f) {
    u32 u = __float_as_uint(f);
    u32 lsb = (u >> 16) & 1u;
    u += 0x7fffu + lsb;
    return (u16)(u >> 16);
}
// packed fp32x2 -> bf16x2 (RNE). Hardware v_cvt_pk_bf16_f32 on gfx950.
__device__ __forceinline__ u32 pkbf(float lo, float hi) {
#if __has_builtin(__builtin_amdgcn_cvt_pk_bf16_f32)
    auto r = __builtin_amdgcn_cvt_pk_bf16_f32(lo, hi);
    u32 u; __builtin_memcpy(&u, &r, 4); return u;
#else
    return (u32)f2bf(lo) | ((u32)f2bf(hi) << 16);
#endif
}
__device__ __forceinline__ float silu_f(float x) {
    // x * sigmoid(x) with native exp/rcp (~1e-6 rel err, fine vs bf16 noise)
    return x * __builtin_amdgcn_rcpf(1.0f + __expf(-x));
}
__device__ __forceinline__ bf16x8 ldfrag(const u16* p) {
    return *(const bf16x8*)__builtin_assume_aligned(p, 16);
}
__device__ __forceinline__ u64 shfl_xor_u64(u64 v, int mask) {
    u32 lo = (u32)v, hi = (u32)(v >> 32);
    lo = (u32)__shfl_xor((int)lo, mask, 64);
    hi = (u32)__shfl_xor((int)hi, mask, 64);
    return ((u64)hi << 32) | lo;
}

// ---------------------------------------------------------------------------
// K0: dtype probe (fp32 vs bf16 float inputs)
// ---------------------------------------------------------------------------
__global__ void probe_kernel(const u16* __restrict__ raw, int* __restrict__ flag) {
    __shared__ int s;
    int t = threadIdx.x;
    if (t == 0) s = 0;
    __syncthreads();
    float x = bf2f(raw[2 * t]);
    if (!(fabsf(x) < 1000.0f)) atomicOr(&s, 1);
    __syncthreads();
    if (t == 0) *flag = s;
}

// ---------------------------------------------------------------------------
// K0b: ingest small fp32-canonical arrays.
// ---------------------------------------------------------------------------
#define NARR 10
struct IngestDesc {
    const void* src[NARR];
    void*       dst[NARR];
    int         n[NARR];
};

__global__ void ingest_kernel(IngestDesc d, const int* __restrict__ flag, int total) {
    int gid = blockIdx.x * blockDim.x + threadIdx.x;
    if (gid >= total) return;
    int a = 0, off = gid;
    while (off >= d.n[a]) { off -= d.n[a]; ++a; }
    bool f32in = (*flag != 0);
    float v = f32in ? ((const float*)d.src[a])[off]
                    : bf2f(((const u16*)d.src[a])[off]);
    ((float*)d.dst[a])[off] = v;
}

// ---------------------------------------------------------------------------
// K0c: weight prep — transpose to [n][k] bf16 for MFMA B-operands.
// ---------------------------------------------------------------------------
__global__ void prep_weights(const void* __restrict__ l1w, const void* __restrict__ l2w,
                             const void* __restrict__ mw2, const void* __restrict__ mw1,
                             u16* __restrict__ l1wt, u16* __restrict__ l2wt,
                             u16* __restrict__ mw2t, u16* __restrict__ mw1t,
                             const int* __restrict__ flag) {
    int gid = blockIdx.x * blockDim.x + threadIdx.x;
    bool f32in = (*flag != 0);
    if (gid < 3 * 98304) {
        int seg = gid / 98304;
        int t = gid % 98304;
        int l = t >> 14;
        int n = (t >> 7) & 127;
        int k = t & 127;
        const void* src = (seg == 0) ? l1w : ((seg == 1) ? l2w : mw2);
        u16* dst = (seg == 0) ? l1wt : ((seg == 1) ? l2wt : mw2t);
        int si = l * 16384 + k * 128 + n;
        float v = f32in ? ((const float*)src)[si] : bf2f(((const u16*)src)[si]);
        dst[t] = f2bf(v);
    } else {
        int t = gid - 3 * 98304;
        if (t < 49152) {
            int l = t >> 13;
            int n = (t >> 6) & 127;
            int k = t & 63;
            float v = 0.0f;
            if (k < 50) {
                int si = l * 6400 + k * 128 + n;
                v = f32in ? ((const float*)mw1)[si] : bf2f(((const u16*)mw1)[si]);
            }
            mw1t[t] = f2bf(v);
        }
    }
}

// ---------------------------------------------------------------------------
// K1: graph build, one WAVE per center atom. u64 (d2,j) keys, butterfly min
// x32 == jax.lax.top_k order. Also builds reverse adjacency.
// ---------------------------------------------------------------------------
__launch_bounds__(256)
__global__ void build_graph_kernel(const float* __restrict__ pos,
                                   float* __restrict__ dist,
                                   float* __restrict__ cvalp,
                                   int* __restrict__ rev_cnt,
                                   int* __restrict__ rev_e) {
    int wv = threadIdx.x >> 6, lane = threadIdx.x & 63;
    int t = blockIdx.x * 4 + wv;
    int tl = t & 127;
    int base = t & ~127;
    float cx = pos[t * 3 + 0];
    float cy = pos[t * 3 + 1];
    float cz = pos[t * 3 + 2];
    u64 key[2];
#pragma unroll
    for (int c = 0; c < 2; ++c) {
        int j = lane + c * 64;
        float jx = pos[(base + j) * 3 + 0];
        float jy = pos[(base + j) * 3 + 1];
        float jz = pos[(base + j) * 3 + 2];
        float dx = __fsub_rn(cx, jx);
        float dy = __fsub_rn(cy, jy);
        float dz = __fsub_rn(cz, jz);
        float d2 = __fadd_rn(__fadd_rn(__fmul_rn(dx, dx), __fmul_rn(dy, dy)),
                             __fmul_rn(dz, dz));
        bool valid = (j != tl) && (d2 < 100.0f);
        key[c] = valid ? ((((u64)__float_as_uint(d2)) << 32) | (u32)j) : ~0ULL;
    }
    for (int k = 0; k < KNN; ++k) {
        u64 m = key[0] < key[1] ? key[0] : key[1];
#pragma unroll
        for (int off = 32; off > 0; off >>= 1) {
            u64 o = shfl_xor_u64(m, off);
            if (o < m) m = o;
        }
        int e = t * KNN + k;
        if (m == ~0ULL) {
            if (lane == 0) { dist[e] = 1.0f; cvalp[e] = 0.0f; }
        } else {
            if (key[0] == m) key[0] = ~0ULL;
            if (key[1] == m) key[1] = ~0ULL;
            if (lane == (int)(m & 63)) {
                float d2 = __uint_as_float((u32)(m >> 32));
                float d = __fsqrt_rn(d2);
                float cv = (d < 10.0f) ? 0.5f * (cosf(d * 3.14159265f / 10.0f) + 1.0f)
                                       : 0.0f;
                dist[e] = d;
                cvalp[e] = cv;
                int j = base + (int)(m & 0xffffffffu);
                int p = atomicAdd(&rev_cnt[j], 1);
                rev_e[(size_t)j * 128 + p] = e;
            }
        }
    }
}

// ---------------------------------------------------------------------------
// K2: embedding gather
// ---------------------------------------------------------------------------
__global__ void embed_kernel(const int* __restrict__ z,
                             const float* __restrict__ emb,
                             float* __restrict__ h) {
    int i = blockIdx.x, t = threadIdx.x;
    h[(size_t)i * HID + t] = emb[(size_t)z[i] * HID + t];
}

// ---------------------------------------------------------------------------
// K3: dense MFMA GEMM, O[8192,128] = A @ Bt^T + bias. SPLIT=1: A as hi+lo
// bf16 pair (fp32-ish precision, h path). SPLIT=0: single bf16 (xj path).
// MODE 0: O = res; MODE 1: O += silu(res).
// ---------------------------------------------------------------------------
template <int MODE, int SPLIT>
__launch_bounds__(256)
__global__ void gemm_mfma(const float* __restrict__ A,
                          const u16* __restrict__ Bt,
                          const float* __restrict__ bias,
                          float* __restrict__ O) {
    __shared__ u16 s_ahi[32 * PAD128];
    __shared__ u16 s_alo[SPLIT ? 32 * PAD128 : 2];
    __shared__ u16 s_b[128 * PAD128];
    __shared__ float s_bias[128];
    int tid = threadIdx.x;
    int row0 = blockIdx.x * 32;
    {
        const float4* src = (const float4*)(A + (size_t)row0 * 128);
        for (int p = 0; p < 4; ++p) {
            int q = tid + p * 256;
            int r = q >> 5, k4 = (q & 31) * 4;
            float4 v = src[q];
            u32 h0 = pkbf(v.x, v.y), h1 = pkbf(v.z, v.w);
            u32* hd = (u32*)&s_ahi[r * PAD128 + k4];
            hd[0] = h0; hd[1] = h1;
            if (SPLIT) {
                u32 l0 = pkbf(v.x - bf2f((u16)h0), v.y - bf2f((u16)(h0 >> 16)));
                u32 l1 = pkbf(v.z - bf2f((u16)h1), v.w - bf2f((u16)(h1 >> 16)));
                u32* ld = (u32*)&s_alo[r * PAD128 + k4];
                ld[0] = l0; ld[1] = l1;
            }
        }
    }
    {
        const uint4* src = (const uint4*)Bt;
        for (int p = 0; p < 8; ++p) {
            int q = tid + p * 256;
            int r = q >> 4, c8 = (q & 15) * 8;
            *(uint4*)&s_b[r * PAD128 + c8] = src[q];
        }
    }
    if (tid < 128) s_bias[tid] = bias[tid];
    __syncthreads();

    int wv = tid >> 6, lane = tid & 63;
    int quad = lane >> 4, lr = lane & 15;
    int n0 = wv * 32;
    f32x4 acc[2][2];
#pragma unroll
    for (int mt = 0; mt < 2; ++mt)
#pragma unroll
        for (int nt = 0; nt < 2; ++nt) acc[mt][nt] = (f32x4){0.f, 0.f, 0.f, 0.f};
#pragma unroll
    for (int kk = 0; kk < 128; kk += 32) {
        bf16x8 ah0 = ldfrag(&s_ahi[(lr)      * PAD128 + kk + quad * 8]);
        bf16x8 ah1 = ldfrag(&s_ahi[(16 + lr) * PAD128 + kk + quad * 8]);
#pragma unroll
        for (int nt = 0; nt < 2; ++nt) {
            bf16x8 b = ldfrag(&s_b[(n0 + nt * 16 + lr) * PAD128 + kk + quad * 8]);
            acc[0][nt] = __builtin_amdgcn_mfma_f32_16x16x32_bf16(ah0, b, acc[0][nt], 0, 0, 0);
            acc[1][nt] = __builtin_amdgcn_mfma_f32_16x16x32_bf16(ah1, b, acc[1][nt], 0, 0, 0);
        }
        if (SPLIT) {
            bf16x8 al0 = ldfrag(&s_alo[(lr)      * PAD128 + kk + quad * 8]);
            bf16x8 al1 = ldfrag(&s_alo[(16 + lr) * PAD128 + kk + quad * 8]);
#pragma unroll
            for (int nt = 0; nt < 2; ++nt) {
                bf16x8 b = ldfrag(&s_b[(n0 + nt * 16 + lr) * PAD128 + kk + quad * 8]);
                acc[0][nt] = __builtin_amdgcn_mfma_f32_16x16x32_bf16(al0, b, acc[0][nt], 0, 0, 0);
                acc[1][nt] = __builtin_amdgcn_mfma_f32_16x16x32_bf16(al1, b, acc[1][nt], 0, 0, 0);
            }
        }
    }
#pragma unroll
    for (int mt = 0; mt < 2; ++mt)
#pragma unroll
        for (int nt = 0; nt < 2; ++nt)
#pragma unroll
            for (int r = 0; r < 4; ++r) {
                int grow = row0 + mt * 16 + quad * 4 + r;
                int col = n0 + nt * 16 + lr;
                float v = acc[mt][nt][r] + s_bias[col];
                size_t off = (size_t)grow * 128 + col;
                if (MODE == 0) O[off] = v;
                else           O[off] += silu_f(v);
            }
}

// ---------------------------------------------------------------------------
// K4: W/msg producer. Block = 128 edges (4 centers, one per wave). rbf frags
// in registers (native exp); w1/w2 B-frags straight from global (L2-hot).
// Each wave's Phase B reads only its own 32 t1 rows -> no barrier between
// phases. Packed bf16 conversions throughout.
// ---------------------------------------------------------------------------
__launch_bounds__(256)
__global__ void wcompute_kernel(const float* __restrict__ dist,
                                const float* __restrict__ cval,
                                const float* __restrict__ xj,
                                const u16* __restrict__ mw1t,   // [128][64]
                                const u16* __restrict__ mw2t,   // [128][128]
                                const float* __restrict__ b1,
                                const float* __restrict__ b2,
                                u16* __restrict__ msg) {        // [262144][128]
    __shared__ u16 s_t1[128 * PAD128];     // 34.8 KB
    __shared__ float s_xj[4 * 128];
    __shared__ float s_cv[128];
    __shared__ float s_d[128];
    __shared__ float s_b1[128], s_b2[128];

    int tid = threadIdx.x;
    int eb0 = blockIdx.x * 128;
    if (tid < 128) {
        s_d[tid]  = dist[eb0 + tid];
        s_cv[tid] = cval[eb0 + tid];
        s_b1[tid] = b1[tid];
        s_b2[tid] = b2[tid];
        const float4* src = (const float4*)(xj + (size_t)(blockIdx.x * 4) * 128);
        ((float4*)s_xj)[tid] = src[tid];
    }
    __syncthreads();

    int wv = tid >> 6, lane = tid & 63;
    int quad = lane >> 4, lr = lane & 15;
    int m0 = wv * 32;

    // Phase A: t1 = silu(rbf @ mw1 + b1), rbf per-lane in registers
    {
        const float wgi = 49.0f / 10.0f;
        union U8 { bf16x8 v; u32 w[4]; };
        U8 afr[2][2];                      // [mt][kki]
#pragma unroll
        for (int mt = 0; mt < 2; ++mt) {
            float u = s_d[m0 + mt * 16 + lr] * wgi;    // d/width
            float kb = (float)(quad * 8);
#pragma unroll
            for (int kki = 0; kki < 2; ++kki) {
                float t0 = u - kb - (float)(kki * 32);
                float vj[8];
#pragma unroll
                for (int j = 0; j < 8; ++j) {
                    float tt = t0 - (float)j;
                    float e = __expf(-0.5f * tt * tt);
                    if (kki == 1 && (quad * 8 + j) >= 18) e = 0.0f;  // k>=50 pad
                    vj[j] = e;
                }
#pragma unroll
                for (int p = 0; p < 4; ++p)
                    afr[mt][kki].w[p] = pkbf(vj[2 * p], vj[2 * p + 1]);
            }
        }
        f32x4 accA[2][8];
#pragma unroll
        for (int mt = 0; mt < 2; ++mt)
#pragma unroll
            for (int nt = 0; nt < 8; ++nt) accA[mt][nt] = (f32x4){0.f, 0.f, 0.f, 0.f};
#pragma unroll
        for (int kki = 0; kki < 2; ++kki) {
#pragma unroll
            for (int nt = 0; nt < 8; ++nt) {
                bf16x8 b = ldfrag(mw1t + (nt * 16 + lr) * 64 + kki * 32 + quad * 8);
                accA[0][nt] = __builtin_amdgcn_mfma_f32_16x16x32_bf16(afr[0][kki].v, b, accA[0][nt], 0, 0, 0);
                accA[1][nt] = __builtin_amdgcn_mfma_f32_16x16x32_bf16(afr[1][kki].v, b, accA[1][nt], 0, 0, 0);
            }
        }
#pragma unroll
        for (int mt = 0; mt < 2; ++mt) {
            int r0 = m0 + mt * 16 + quad * 4;
            u16* tp0 = &s_t1[r0 * PAD128 + lr];
#pragma unroll
            for (int nt = 0; nt < 8; ++nt) {
                int col = nt * 16;
                float bb = s_b1[col + lr];
                u32 p01 = pkbf(silu_f(accA[mt][nt][0] + bb),
                               silu_f(accA[mt][nt][1] + bb));
                u32 p23 = pkbf(silu_f(accA[mt][nt][2] + bb),
                               silu_f(accA[mt][nt][3] + bb));
                u16* tp = tp0 + col;
                tp[0]          = (u16)p01;
                tp[PAD128]     = (u16)(p01 >> 16);
                tp[2 * PAD128] = (u16)p23;
                tp[3 * PAD128] = (u16)(p23 >> 16);
            }
        }
    }
    // no barrier: each wave's Phase B A-frags read only rows [m0, m0+32)
    // which this wave itself wrote above (same-wave DS ordering).

    // Phase B: msg = (t1 @ mw2 + b2) * cv * xj
    {
        f32x4 accB[2][8];
#pragma unroll
        for (int mt = 0; mt < 2; ++mt)
#pragma unroll
            for (int nt = 0; nt < 8; ++nt) accB[mt][nt] = (f32x4){0.f, 0.f, 0.f, 0.f};
#pragma unroll
        for (int kk = 0; kk < 128; kk += 32) {
            bf16x8 a0 = ldfrag(&s_t1[(m0 + lr)      * PAD128 + kk + quad * 8]);
            bf16x8 a1 = ldfrag(&s_t1[(m0 + 16 + lr) * PAD128 + kk + quad * 8]);
#pragma unroll
            for (int nt = 0; nt < 8; ++nt) {
                bf16x8 b = ldfrag(mw2t + (nt * 16 + lr) * 128 + kk + quad * 8);
                accB[0][nt] = __builtin_amdgcn_mfma_f32_16x16x32_bf16(a0, b, accB[0][nt], 0, 0, 0);
                accB[1][nt] = __builtin_amdgcn_mfma_f32_16x16x32_bf16(a1, b, accB[1][nt], 0, 0, 0);
            }
        }
#pragma unroll
        for (int mt = 0; mt < 2; ++mt) {
            int r0 = m0 + mt * 16 + quad * 4;
            float c0 = s_cv[r0], c1 = s_cv[r0 + 1], c2 = s_cv[r0 + 2], c3 = s_cv[r0 + 3];
            u16* bp = msg + (size_t)(eb0 + r0) * 128 + lr;
#pragma unroll
            for (int nt = 0; nt < 8; ++nt) {
                int col = nt * 16;
                float bb = s_b2[col + lr];
                float xv = s_xj[wv * 128 + col + lr];
                u32 p01 = pkbf((accB[mt][nt][0] + bb) * c0 * xv,
                               (accB[mt][nt][1] + bb) * c1 * xv);
                u32 p23 = pkbf((accB[mt][nt][2] + bb) * c2 * xv,
                               (accB[mt][nt][3] + bb) * c3 * xv);
                bp[col]           = (u16)p01;
                bp[col + 128]     = (u16)(p01 >> 16);
                bp[col + 256]     = (u16)p23;
                bp[col + 384]     = (u16)(p23 >> 16);
            }
        }
    }
}

// ---------------------------------------------------------------------------
// K5: gather — agg[j] = sum over incoming edges of msg[e]. Unrolled x4 for
// memory-level parallelism; no atomics.
// ---------------------------------------------------------------------------
__launch_bounds__(256)
__global__ void gather_kernel(const int* __restrict__ rev_cnt,
                              const int* __restrict__ rev_e,
                              const u16* __restrict__ msg,
                              float* __restrict__ agg) {
    int j = blockIdx.x * 4 + (threadIdx.x >> 6);
    int lane = threadIdx.x & 63;
    int deg = rev_cnt[j];
    const int* lst = rev_e + (size_t)j * 128;
    float s0 = 0.f, s1 = 0.f, s2 = 0.f, s3 = 0.f;
    float t0 = 0.f, t1 = 0.f, t2 = 0.f, t3 = 0.f;
    int it = 0;
    for (; it + 4 <= deg; it += 4) {
        int4 e4 = *(const int4*)(lst + it);
        ushort2 m0 = *(const ushort2*)(msg + (size_t)e4.x * 128 + lane * 2);
        ushort2 m1 = *(const ushort2*)(msg + (size_t)e4.y * 128 + lane * 2);
        ushort2 m2 = *(const ushort2*)(msg + (size_t)e4.z * 128 + lane * 2);
        ushort2 m3 = *(const ushort2*)(msg + (size_t)e4.w * 128 + lane * 2);
        s0 += bf2f(m0.x); t0 += bf2f(m0.y);
        s1 += bf2f(m1.x); t1 += bf2f(m1.y);
        s2 += bf2f(m2.x); t2 += bf2f(m2.y);
        s3 += bf2f(m3.x); t3 += bf2f(m3.y);
    }
    for (; it < deg; ++it) {
        int e = lst[it];
        ushort2 m = *(const ushort2*)(msg + (size_t)e * 128 + lane * 2);
        s0 += bf2f(m.x); t0 += bf2f(m.y);
    }
    float2 r;
    r.x = (s0 + s1) + (s2 + s3);
    r.y = (t0 + t1) + (t2 + t3);
    *(float2*)(agg + (size_t)j * 128 + lane * 2) = r;
}

// ---------------------------------------------------------------------------
// K6: output head + finalize
// ---------------------------------------------------------------------------
__launch_bounds__(64)
__global__ void head_kernel(const float* __restrict__ h,
                            const float* __restrict__ ow1,
                            const float* __restrict__ ob1,
                            const float* __restrict__ ow2,
                            const float* __restrict__ ob2,
                            float* __restrict__ gsum) {
    int i = blockIdx.x;
    int c = threadIdx.x;
    const float* hrow = h + (size_t)i * 128;
    float o = ob1[c];
#pragma unroll 4
    for (int f = 0; f < 128; ++f) o += hrow[f] * ow1[f * 64 + c];
    o = silu_f(o);
    float v = o * ow2[c];
    for (int off = 32; off > 0; off >>= 1) v += __shfl_down(v, off, 64);
    if (c == 0) {
        int g = i >> 7;
        atomicAdd(&gsum[g], v + ob2[0]);
    }
}

__global__ void finalize_kernel(const float* __restrict__ gsum, void* __restrict__ out,
                                const int* __restrict__ flag) {
    int t = threadIdx.x;
    if (*flag) ((float*)out)[t] = gsum[t];
    else       ((u16*)out)[t]   = f2bf(gsum[t]);
}

// ---------------------------------------------------------------------------
extern "C" void kernel_launch(void* const* d_in, const int* in_sizes, int n_in,
                              void* d_out, int out_size, void* d_ws, size_t ws_size,
                              hipStream_t stream) {
    const void* pos  = d_in[0];
    const int*  z    = (const int*)d_in[1];
    // d_in[2] = batch (implicit: graph = i >> 7)
    const void* emb  = d_in[3];
    const void* mw1  = d_in[4];
    const void* mb1  = d_in[5];
    const void* mw2  = d_in[6];
    const void* mb2  = d_in[7];
    const void* l1w  = d_in[8];
    const void* l1b  = d_in[9];
    const void* l2w  = d_in[10];
    const void* l2b  = d_in[11];
    const void* ow1  = d_in[12];
    const void* ob1  = d_in[13];
    const void* ow2  = d_in[14];
    const void* ob2  = d_in[15];

    char* ws = (char*)d_ws;
    const size_t KB = 1024, MB = 1048576;
    int*   w_flag  = (int*)  (ws);
    float* c_pos   = (float*)(ws + 4   * KB);
    float* c_emb   = (float*)(ws + 112 * KB);
    float* c_mb1   = (float*)(ws + 168 * KB);
    float* c_mb2   = (float*)(ws + 172 * KB);
    float* c_l1b   = (float*)(ws + 176 * KB);
    float* c_l2b   = (float*)(ws + 180 * KB);
    float* c_ow1   = (float*)(ws + 184 * KB);
    float* c_ob1   = (float*)(ws + 220 * KB);
    float* c_ow2   = (float*)(ws + 221 * KB);
    float* c_ob2   = (float*)(ws + 222 * KB);
    float* w_gsum  = (float*)(ws + 224 * KB);
    u16*   c_l1wt  = (u16*)  (ws + 256 * KB);
    u16*   c_l2wt  = (u16*)  (ws + 448 * KB);
    u16*   c_mw2t  = (u16*)  (ws + 640 * KB);
    u16*   c_mw1t  = (u16*)  (ws + 832 * KB);
    float* w_dist  = (float*)(ws + 1  * MB);
    float* w_cval  = (float*)(ws + 2  * MB);
    int*   rev_cnt = (int*)  (ws + 3  * MB);
    int*   rev_e   = (int*)  (ws + 4  * MB);
    float* w_h     = (float*)(ws + 8  * MB);
    float* w_xj    = (float*)(ws + 12 * MB);
    float* w_agg   = (float*)(ws + 16 * MB);
    u16*   w_msg   = (u16*)  (ws + 20 * MB);   // 64 MB

    hipMemsetAsync(rev_cnt, 0, NATOMS * sizeof(int), stream);
    hipMemsetAsync(w_gsum, 0, GRAPHS * sizeof(float), stream);

    probe_kernel<<<1, 256, 0, stream>>>((const u16*)emb, w_flag);

    IngestDesc dsc;
    const void* srcs[NARR] = {pos, emb, mb1, mb2, l1b, l2b, ow1, ob1, ow2, ob2};
    void* dsts[NARR] = {c_pos, c_emb, c_mb1, c_mb2, c_l1b, c_l2b, c_ow1, c_ob1,
                        c_ow2, c_ob2};
    int ns[NARR] = {24576, 12800, 768, 768, 768, 768, 8192, 64, 64, 1};
    int total = 0;
    for (int a = 0; a < NARR; ++a) {
        dsc.src[a] = srcs[a]; dsc.dst[a] = dsts[a]; dsc.n[a] = ns[a];
        total += ns[a];
    }
    ingest_kernel<<<(total + 255) / 256, 256, 0, stream>>>(dsc, w_flag, total);
    prep_weights<<<1344, 256, 0, stream>>>(l1w, l2w, mw2, mw1,
                                           c_l1wt, c_l2wt, c_mw2t, c_mw1t, w_flag);

    build_graph_kernel<<<NATOMS / 4, 256, 0, stream>>>(c_pos, w_dist, w_cval,
                                                       rev_cnt, rev_e);
    embed_kernel<<<NATOMS, HID, 0, stream>>>(z, c_emb, w_h);

    for (int l = 0; l < LAYERS; ++l) {
        gemm_mfma<0, 0><<<NATOMS / 32, 256, 0, stream>>>(
            w_h, c_l1wt + (size_t)l * 16384, c_l1b + (size_t)l * 128, w_xj);
        wcompute_kernel<<<NATOMS * KNN / 128, 256, 0, stream>>>(
            w_dist, w_cval, w_xj,
            c_mw1t + (size_t)l * 8192, c_mw2t + (size_t)l * 16384,
            c_mb1 + (size_t)l * 128, c_mb2 + (size_t)l * 128, w_msg);
        gather_kernel<<<NATOMS / 4, 256, 0, stream>>>(rev_cnt, rev_e, w_msg, w_agg);
        gemm_mfma<1, 1><<<NATOMS / 32, 256, 0, stream>>>(
            w_agg, c_l2wt + (size_t)l * 16384, c_l2b + (size_t)l * 128, w_h);
    }

    head_kernel<<<NATOMS, 64, 0, stream>>>(w_h, c_ow1, c_ob1, c_ow2, c_ob2, w_gsum);
    finalize_kernel<<<1, GRAPHS, 0, stream>>>(w_gsum, (void*)d_out, w_flag);
}

// Round 6
// 668.580 us; speedup vs baseline: 5.6896x; 1.0542x over previous
//
#include <hip/hip_runtime.h>
#include <math.h>

typedef unsigned short u16;
typedef unsigned int   u32;
typedef unsigned long long u64;

#define NATOMS 8192
#define GRAPHS 64
#define APG    128
#define KNN    32
#define NGAUSS 50
#define HID    128
#define LAYERS 6
#define PAD128 136

typedef __attribute__((ext_vector_type(8))) short bf16x8;
typedef __attribute__((ext_vector_type(4))) float f32x4;

__device__ __forceinline__ float bf2f(u16 v) {
    return __uint_as_float(((u32)v) << 16);
}
__device__ __forceinline__ u16 f2bf(float f) {
    u32 u = __float_as_uint(f);
    u32 lsb = (u >> 16) & 1u;
    u += 0x7fffu + lsb;
    return (u16)(u >> 16);
}
// packed fp32x2 -> bf16x2 (RNE). Hardware v_cvt_pk_bf16_f32 on gfx950.
__device__ __forceinline__ u32 pkbf(float lo, float hi) {
#if __has_builtin(__builtin_amdgcn_cvt_pk_bf16_f32)
    auto r = __builtin_amdgcn_cvt_pk_bf16_f32(lo, hi);
    u32 u; __builtin_memcpy(&u, &r, 4); return u;
#else
    return (u32)f2bf(lo) | ((u32)f2bf(hi) << 16);
#endif
}
__device__ __forceinline__ float silu_f(float x) {
    return x * __builtin_amdgcn_rcpf(1.0f + __expf(-x));
}
__device__ __forceinline__ bf16x8 ldfrag(const u16* p) {
    return *(const bf16x8*)__builtin_assume_aligned(p, 16);
}
__device__ __forceinline__ u64 shfl_xor_u64(u64 v, int mask) {
    u32 lo = (u32)v, hi = (u32)(v >> 32);
    lo = (u32)__shfl_xor((int)lo, mask, 64);
    hi = (u32)__shfl_xor((int)hi, mask, 64);
    return ((u64)hi << 32) | lo;
}

// ---------------------------------------------------------------------------
// K0: dtype probe (fp32 vs bf16 float inputs)
// ---------------------------------------------------------------------------
__global__ void probe_kernel(const u16* __restrict__ raw, int* __restrict__ flag) {
    __shared__ int s;
    int t = threadIdx.x;
    if (t == 0) s = 0;
    __syncthreads();
    float x = bf2f(raw[2 * t]);
    if (!(fabsf(x) < 1000.0f)) atomicOr(&s, 1);
    __syncthreads();
    if (t == 0) *flag = s;
}

// ---------------------------------------------------------------------------
// K0b: ingest small fp32-canonical arrays.
// ---------------------------------------------------------------------------
#define NARR 10
struct IngestDesc {
    const void* src[NARR];
    void*       dst[NARR];
    int         n[NARR];
};

__global__ void ingest_kernel(IngestDesc d, const int* __restrict__ flag, int total) {
    int gid = blockIdx.x * blockDim.x + threadIdx.x;
    if (gid >= total) return;
    int a = 0, off = gid;
    while (off >= d.n[a]) { off -= d.n[a]; ++a; }
    bool f32in = (*flag != 0);
    float v = f32in ? ((const float*)d.src[a])[off]
                    : bf2f(((const u16*)d.src[a])[off]);
    ((float*)d.dst[a])[off] = v;
}

// ---------------------------------------------------------------------------
// K0c: weight prep — transpose to [n][k] bf16 for MFMA B-operands.
// ---------------------------------------------------------------------------
__global__ void prep_weights(const void* __restrict__ l1w, const void* __restrict__ l2w,
                             const void* __restrict__ mw2, const void* __restrict__ mw1,
                             u16* __restrict__ l1wt, u16* __restrict__ l2wt,
                             u16* __restrict__ mw2t, u16* __restrict__ mw1t,
                             const int* __restrict__ flag) {
    int gid = blockIdx.x * blockDim.x + threadIdx.x;
    bool f32in = (*flag != 0);
    if (gid < 3 * 98304) {
        int seg = gid / 98304;
        int t = gid % 98304;
        int l = t >> 14;
        int n = (t >> 7) & 127;
        int k = t & 127;
        const void* src = (seg == 0) ? l1w : ((seg == 1) ? l2w : mw2);
        u16* dst = (seg == 0) ? l1wt : ((seg == 1) ? l2wt : mw2t);
        int si = l * 16384 + k * 128 + n;
        float v = f32in ? ((const float*)src)[si] : bf2f(((const u16*)src)[si]);
        dst[t] = f2bf(v);
    } else {
        int t = gid - 3 * 98304;
        if (t < 49152) {
            int l = t >> 13;
            int n = (t >> 6) & 127;
            int k = t & 63;
            float v = 0.0f;
            if (k < 50) {
                int si = l * 6400 + k * 128 + n;
                v = f32in ? ((const float*)mw1)[si] : bf2f(((const u16*)mw1)[si]);
            }
            mw1t[t] = f2bf(v);
        }
    }
}

// ---------------------------------------------------------------------------
// K1: graph build, one WAVE per center atom. u64 (d2,j) keys, butterfly min
// x32 == jax.lax.top_k order. Also builds reverse adjacency.
// ---------------------------------------------------------------------------
__launch_bounds__(256)
__global__ void build_graph_kernel(const float* __restrict__ pos,
                                   float* __restrict__ dist,
                                   float* __restrict__ cvalp,
                                   int* __restrict__ rev_cnt,
                                   int* __restrict__ rev_e) {
    int wv = threadIdx.x >> 6, lane = threadIdx.x & 63;
    int t = blockIdx.x * 4 + wv;
    int tl = t & 127;
    int base = t & ~127;
    float cx = pos[t * 3 + 0];
    float cy = pos[t * 3 + 1];
    float cz = pos[t * 3 + 2];
    u64 key[2];
#pragma unroll
    for (int c = 0; c < 2; ++c) {
        int j = lane + c * 64;
        float jx = pos[(base + j) * 3 + 0];
        float jy = pos[(base + j) * 3 + 1];
        float jz = pos[(base + j) * 3 + 2];
        float dx = __fsub_rn(cx, jx);
        float dy = __fsub_rn(cy, jy);
        float dz = __fsub_rn(cz, jz);
        float d2 = __fadd_rn(__fadd_rn(__fmul_rn(dx, dx), __fmul_rn(dy, dy)),
                             __fmul_rn(dz, dz));
        bool valid = (j != tl) && (d2 < 100.0f);
        key[c] = valid ? ((((u64)__float_as_uint(d2)) << 32) | (u32)j) : ~0ULL;
    }
    for (int k = 0; k < KNN; ++k) {
        u64 m = key[0] < key[1] ? key[0] : key[1];
#pragma unroll
        for (int off = 32; off > 0; off >>= 1) {
            u64 o = shfl_xor_u64(m, off);
            if (o < m) m = o;
        }
        int e = t * KNN + k;
        if (m == ~0ULL) {
            if (lane == 0) { dist[e] = 1.0f; cvalp[e] = 0.0f; }
        } else {
            if (key[0] == m) key[0] = ~0ULL;
            if (key[1] == m) key[1] = ~0ULL;
            if (lane == (int)(m & 63)) {
                float d2 = __uint_as_float((u32)(m >> 32));
                float d = __fsqrt_rn(d2);
                float cv = (d < 10.0f) ? 0.5f * (cosf(d * 3.14159265f / 10.0f) + 1.0f)
                                       : 0.0f;
                dist[e] = d;
                cvalp[e] = cv;
                int j = base + (int)(m & 0xffffffffu);
                int p = atomicAdd(&rev_cnt[j], 1);
                rev_e[(size_t)j * 128 + p] = e;
            }
        }
    }
}

// ---------------------------------------------------------------------------
// K2: embedding gather
// ---------------------------------------------------------------------------
__global__ void embed_kernel(const int* __restrict__ z,
                             const float* __restrict__ emb,
                             float* __restrict__ h) {
    int i = blockIdx.x, t = threadIdx.x;
    h[(size_t)i * HID + t] = emb[(size_t)z[i] * HID + t];
}

// ---------------------------------------------------------------------------
// K3: dense MFMA GEMM, O[8192,128] = A @ Bt^T + bias. SPLIT=1: A as hi+lo
// bf16 pair (fp32-ish precision, h path). SPLIT=0: single bf16 (xj path).
// MODE 0: O = res; MODE 1: O += silu(res).
// ---------------------------------------------------------------------------
template <int MODE, int SPLIT>
__launch_bounds__(256)
__global__ void gemm_mfma(const float* __restrict__ A,
                          const u16* __restrict__ Bt,
                          const float* __restrict__ bias,
                          float* __restrict__ O) {
    __shared__ u16 s_ahi[32 * PAD128];
    __shared__ u16 s_alo[SPLIT ? 32 * PAD128 : 2];
    __shared__ u16 s_b[128 * PAD128];
    __shared__ float s_bias[128];
    int tid = threadIdx.x;
    int row0 = blockIdx.x * 32;
    {
        const float4* src = (const float4*)(A + (size_t)row0 * 128);
        for (int p = 0; p < 4; ++p) {
            int q = tid + p * 256;
            int r = q >> 5, k4 = (q & 31) * 4;
            float4 v = src[q];
            u32 h0 = pkbf(v.x, v.y), h1 = pkbf(v.z, v.w);
            u32* hd = (u32*)&s_ahi[r * PAD128 + k4];
            hd[0] = h0; hd[1] = h1;
            if (SPLIT) {
                u32 l0 = pkbf(v.x - bf2f((u16)h0), v.y - bf2f((u16)(h0 >> 16)));
                u32 l1 = pkbf(v.z - bf2f((u16)h1), v.w - bf2f((u16)(h1 >> 16)));
                u32* ld = (u32*)&s_alo[r * PAD128 + k4];
                ld[0] = l0; ld[1] = l1;
            }
        }
    }
    {
        const uint4* src = (const uint4*)Bt;
        for (int p = 0; p < 8; ++p) {
            int q = tid + p * 256;
            int r = q >> 4, c8 = (q & 15) * 8;
            *(uint4*)&s_b[r * PAD128 + c8] = src[q];
        }
    }
    if (tid < 128) s_bias[tid] = bias[tid];
    __syncthreads();

    int wv = tid >> 6, lane = tid & 63;
    int quad = lane >> 4, lr = lane & 15;
    int n0 = wv * 32;
    f32x4 acc[2][2];
#pragma unroll
    for (int mt = 0; mt < 2; ++mt)
#pragma unroll
        for (int nt = 0; nt < 2; ++nt) acc[mt][nt] = (f32x4){0.f, 0.f, 0.f, 0.f};
#pragma unroll
    for (int kk = 0; kk < 128; kk += 32) {
        bf16x8 ah0 = ldfrag(&s_ahi[(lr)      * PAD128 + kk + quad * 8]);
        bf16x8 ah1 = ldfrag(&s_ahi[(16 + lr) * PAD128 + kk + quad * 8]);
#pragma unroll
        for (int nt = 0; nt < 2; ++nt) {
            bf16x8 b = ldfrag(&s_b[(n0 + nt * 16 + lr) * PAD128 + kk + quad * 8]);
            acc[0][nt] = __builtin_amdgcn_mfma_f32_16x16x32_bf16(ah0, b, acc[0][nt], 0, 0, 0);
            acc[1][nt] = __builtin_amdgcn_mfma_f32_16x16x32_bf16(ah1, b, acc[1][nt], 0, 0, 0);
        }
        if (SPLIT) {
            bf16x8 al0 = ldfrag(&s_alo[(lr)      * PAD128 + kk + quad * 8]);
            bf16x8 al1 = ldfrag(&s_alo[(16 + lr) * PAD128 + kk + quad * 8]);
#pragma unroll
            for (int nt = 0; nt < 2; ++nt) {
                bf16x8 b = ldfrag(&s_b[(n0 + nt * 16 + lr) * PAD128 + kk + quad * 8]);
                acc[0][nt] = __builtin_amdgcn_mfma_f32_16x16x32_bf16(al0, b, acc[0][nt], 0, 0, 0);
                acc[1][nt] = __builtin_amdgcn_mfma_f32_16x16x32_bf16(al1, b, acc[1][nt], 0, 0, 0);
            }
        }
    }
#pragma unroll
    for (int mt = 0; mt < 2; ++mt)
#pragma unroll
        for (int nt = 0; nt < 2; ++nt)
#pragma unroll
            for (int r = 0; r < 4; ++r) {
                int grow = row0 + mt * 16 + quad * 4 + r;
                int col = n0 + nt * 16 + lr;
                float v = acc[mt][nt][r] + s_bias[col];
                size_t off = (size_t)grow * 128 + col;
                if (MODE == 0) O[off] = v;
                else           O[off] += silu_f(v);
            }
}

// ---------------------------------------------------------------------------
// K4: W/msg producer. Block = 128 edges (4 centers, one per wave). rbf frags
// in registers; w1/w2 B-frags from global (L2-hot). Phase A->B barrier-free
// (wave-private t1 rows). Epilogue stages bf16 msg tile in LDS (reusing
// s_t1) and streams it out as contiguous uint4 — full-line HBM writes.
// ---------------------------------------------------------------------------
__launch_bounds__(256)
__global__ void wcompute_kernel(const float* __restrict__ dist,
                                const float* __restrict__ cval,
                                const float* __restrict__ xj,
                                const u16* __restrict__ mw1t,   // [128][64]
                                const u16* __restrict__ mw2t,   // [128][128]
                                const float* __restrict__ b1,
                                const float* __restrict__ b2,
                                u16* __restrict__ msg) {        // [262144][128]
    __shared__ u16 s_t1[128 * PAD128];     // 34.8 KB (t1, then msg staging)
    __shared__ float s_xj[4 * 128];
    __shared__ float s_cv[128];
    __shared__ float s_d[128];
    __shared__ float s_b1[128], s_b2[128];

    int tid = threadIdx.x;
    int eb0 = blockIdx.x * 128;
    if (tid < 128) {
        s_d[tid]  = dist[eb0 + tid];
        s_cv[tid] = cval[eb0 + tid];
        s_b1[tid] = b1[tid];
        s_b2[tid] = b2[tid];
        const float4* src = (const float4*)(xj + (size_t)(blockIdx.x * 4) * 128);
        ((float4*)s_xj)[tid] = src[tid];
    }
    __syncthreads();

    int wv = tid >> 6, lane = tid & 63;
    int quad = lane >> 4, lr = lane & 15;
    int m0 = wv * 32;

    // Phase A: t1 = silu(rbf @ mw1 + b1), rbf per-lane in registers
    {
        const float wgi = 49.0f / 10.0f;
        union U8 { bf16x8 v; u32 w[4]; };
        U8 afr[2][2];                      // [mt][kki]
#pragma unroll
        for (int mt = 0; mt < 2; ++mt) {
            float u = s_d[m0 + mt * 16 + lr] * wgi;    // d/width
            float kb = (float)(quad * 8);
#pragma unroll
            for (int kki = 0; kki < 2; ++kki) {
                float t0 = u - kb - (float)(kki * 32);
                float vj[8];
#pragma unroll
                for (int j = 0; j < 8; ++j) {
                    float tt = t0 - (float)j;
                    float e = __expf(-0.5f * tt * tt);
                    if (kki == 1 && (quad * 8 + j) >= 18) e = 0.0f;  // k>=50 pad
                    vj[j] = e;
                }
#pragma unroll
                for (int p = 0; p < 4; ++p)
                    afr[mt][kki].w[p] = pkbf(vj[2 * p], vj[2 * p + 1]);
            }
        }
        f32x4 accA[2][8];
#pragma unroll
        for (int mt = 0; mt < 2; ++mt)
#pragma unroll
            for (int nt = 0; nt < 8; ++nt) accA[mt][nt] = (f32x4){0.f, 0.f, 0.f, 0.f};
#pragma unroll
        for (int kki = 0; kki < 2; ++kki) {
#pragma unroll
            for (int nt = 0; nt < 8; ++nt) {
                bf16x8 b = ldfrag(mw1t + (nt * 16 + lr) * 64 + kki * 32 + quad * 8);
                accA[0][nt] = __builtin_amdgcn_mfma_f32_16x16x32_bf16(afr[0][kki].v, b, accA[0][nt], 0, 0, 0);
                accA[1][nt] = __builtin_amdgcn_mfma_f32_16x16x32_bf16(afr[1][kki].v, b, accA[1][nt], 0, 0, 0);
            }
        }
#pragma unroll
        for (int mt = 0; mt < 2; ++mt) {
            int r0 = m0 + mt * 16 + quad * 4;
            u16* tp0 = &s_t1[r0 * PAD128 + lr];
#pragma unroll
            for (int nt = 0; nt < 8; ++nt) {
                int col = nt * 16;
                float bb = s_b1[col + lr];
                u32 p01 = pkbf(silu_f(accA[mt][nt][0] + bb),
                               silu_f(accA[mt][nt][1] + bb));
                u32 p23 = pkbf(silu_f(accA[mt][nt][2] + bb),
                               silu_f(accA[mt][nt][3] + bb));
                u16* tp = tp0 + col;
                tp[0]          = (u16)p01;
                tp[PAD128]     = (u16)(p01 >> 16);
                tp[2 * PAD128] = (u16)p23;
                tp[3 * PAD128] = (u16)(p23 >> 16);
            }
        }
    }
    // no barrier: each wave's Phase B A-frags read only rows this wave wrote.

    // Phase B: msg = (t1 @ mw2 + b2) * cv * xj
    {
        f32x4 accB[2][8];
#pragma unroll
        for (int mt = 0; mt < 2; ++mt)
#pragma unroll
            for (int nt = 0; nt < 8; ++nt) accB[mt][nt] = (f32x4){0.f, 0.f, 0.f, 0.f};
#pragma unroll
        for (int kk = 0; kk < 128; kk += 32) {
            bf16x8 a0 = ldfrag(&s_t1[(m0 + lr)      * PAD128 + kk + quad * 8]);
            bf16x8 a1 = ldfrag(&s_t1[(m0 + 16 + lr) * PAD128 + kk + quad * 8]);
#pragma unroll
            for (int nt = 0; nt < 8; ++nt) {
                bf16x8 b = ldfrag(mw2t + (nt * 16 + lr) * 128 + kk + quad * 8);
                accB[0][nt] = __builtin_amdgcn_mfma_f32_16x16x32_bf16(a0, b, accB[0][nt], 0, 0, 0);
                accB[1][nt] = __builtin_amdgcn_mfma_f32_16x16x32_bf16(a1, b, accB[1][nt], 0, 0, 0);
            }
        }
        __syncthreads();   // all Phase-B t1 reads done before staging overwrites
        u16* s16 = s_t1;   // reuse as unpadded [128][128] staging
#pragma unroll
        for (int mt = 0; mt < 2; ++mt) {
            int r0 = m0 + mt * 16 + quad * 4;
            float c0 = s_cv[r0], c1 = s_cv[r0 + 1], c2 = s_cv[r0 + 2], c3 = s_cv[r0 + 3];
            u16* bp = &s16[r0 * 128 + lr];
#pragma unroll
            for (int nt = 0; nt < 8; ++nt) {
                int col = nt * 16;
                float bb = s_b2[col + lr];
                float xv = s_xj[wv * 128 + col + lr];
                u32 p01 = pkbf((accB[mt][nt][0] + bb) * c0 * xv,
                               (accB[mt][nt][1] + bb) * c1 * xv);
                u32 p23 = pkbf((accB[mt][nt][2] + bb) * c2 * xv,
                               (accB[mt][nt][3] + bb) * c3 * xv);
                bp[col]       = (u16)p01;
                bp[col + 128] = (u16)(p01 >> 16);
                bp[col + 256] = (u16)p23;
                bp[col + 384] = (u16)(p23 >> 16);
            }
        }
        __syncthreads();
        // coalesced stream-out: 2048 uint4 = 32 KB, 1 KB per wave-store
        const uint4* s4 = (const uint4*)s16;
        uint4* dst = (uint4*)(msg + (size_t)eb0 * 128);
#pragma unroll
        for (int p = 0; p < 8; ++p) dst[tid + p * 256] = s4[tid + p * 256];
    }
}

// ---------------------------------------------------------------------------
// K5: gather — agg[j] = sum over incoming edges of msg[e]. Unrolled x4.
// ---------------------------------------------------------------------------
__launch_bounds__(256)
__global__ void gather_kernel(const int* __restrict__ rev_cnt,
                              const int* __restrict__ rev_e,
                              const u16* __restrict__ msg,
                              float* __restrict__ agg) {
    int j = blockIdx.x * 4 + (threadIdx.x >> 6);
    int lane = threadIdx.x & 63;
    int deg = rev_cnt[j];
    const int* lst = rev_e + (size_t)j * 128;
    float s0 = 0.f, s1 = 0.f, s2 = 0.f, s3 = 0.f;
    float t0 = 0.f, t1 = 0.f, t2 = 0.f, t3 = 0.f;
    int it = 0;
    for (; it + 4 <= deg; it += 4) {
        int4 e4 = *(const int4*)(lst + it);
        ushort2 m0 = *(const ushort2*)(msg + (size_t)e4.x * 128 + lane * 2);
        ushort2 m1 = *(const ushort2*)(msg + (size_t)e4.y * 128 + lane * 2);
        ushort2 m2 = *(const ushort2*)(msg + (size_t)e4.z * 128 + lane * 2);
        ushort2 m3 = *(const ushort2*)(msg + (size_t)e4.w * 128 + lane * 2);
        s0 += bf2f(m0.x); t0 += bf2f(m0.y);
        s1 += bf2f(m1.x); t1 += bf2f(m1.y);
        s2 += bf2f(m2.x); t2 += bf2f(m2.y);
        s3 += bf2f(m3.x); t3 += bf2f(m3.y);
    }
    for (; it < deg; ++it) {
        int e = lst[it];
        ushort2 m = *(const ushort2*)(msg + (size_t)e * 128 + lane * 2);
        s0 += bf2f(m.x); t0 += bf2f(m.y);
    }
    float2 r;
    r.x = (s0 + s1) + (s2 + s3);
    r.y = (t0 + t1) + (t2 + t3);
    *(float2*)(agg + (size_t)j * 128 + lane * 2) = r;
}

// ---------------------------------------------------------------------------
// K6: output head — 16 atoms/block, LDS-tiled, one atomic per block.
// ---------------------------------------------------------------------------
__launch_bounds__(256)
__global__ void head_kernel(const float* __restrict__ h,
                            const float* __restrict__ ow1,
                            const float* __restrict__ ob1,
                            const float* __restrict__ ow2,
                            const float* __restrict__ ob2,
                            float* __restrict__ gsum) {
    __shared__ __align__(16) float s_w[128 * 64];   // [f][c], 32 KB
    __shared__ __align__(16) float s_h[16 * 132];   // padded rows
    __shared__ float s_sum;
    int tid = threadIdx.x;
    int a0 = blockIdx.x * 16;
    if (tid == 0) s_sum = 0.0f;
    {
        const float4* src = (const float4*)ow1;
        float4* dst = (float4*)s_w;
#pragma unroll
        for (int p = 0; p < 8; ++p) dst[tid + p * 256] = src[tid + p * 256];
    }
    {
        const float4* src = (const float4*)(h + (size_t)a0 * 128);
#pragma unroll
        for (int p = 0; p < 2; ++p) {
            int q = tid + p * 256;
            int r = q >> 5, c4 = (q & 31) * 4;
            *(float4*)&s_h[r * 132 + c4] = src[q];
        }
    }
    __syncthreads();
    int atom = tid >> 4, cg = tid & 15;
    const float* hr = &s_h[atom * 132];
    const float4* w4 = (const float4*)s_w;
    float4 acc = {0.f, 0.f, 0.f, 0.f};
#pragma unroll 8
    for (int f = 0; f < 128; ++f) {
        float hv = hr[f];
        float4 w = w4[f * 16 + cg];
        acc.x += hv * w.x; acc.y += hv * w.y;
        acc.z += hv * w.z; acc.w += hv * w.w;
    }
    int c0 = cg * 4;
    float v = silu_f(acc.x + ob1[c0 + 0]) * ow2[c0 + 0]
            + silu_f(acc.y + ob1[c0 + 1]) * ow2[c0 + 1]
            + silu_f(acc.z + ob1[c0 + 2]) * ow2[c0 + 2]
            + silu_f(acc.w + ob1[c0 + 3]) * ow2[c0 + 3];
    v += __shfl_xor(v, 1, 64);
    v += __shfl_xor(v, 2, 64);
    v += __shfl_xor(v, 4, 64);
    v += __shfl_xor(v, 8, 64);
    if ((tid & 15) == 0) atomicAdd(&s_sum, v + ob2[0]);   // per-atom sum + ob2
    __syncthreads();
    if (tid == 0) atomicAdd(&gsum[a0 >> 7], s_sum);
}

__global__ void finalize_kernel(const float* __restrict__ gsum, void* __restrict__ out,
                                const int* __restrict__ flag) {
    int t = threadIdx.x;
    if (*flag) ((float*)out)[t] = gsum[t];
    else       ((u16*)out)[t]   = f2bf(gsum[t]);
}

// ---------------------------------------------------------------------------
extern "C" void kernel_launch(void* const* d_in, const int* in_sizes, int n_in,
                              void* d_out, int out_size, void* d_ws, size_t ws_size,
                              hipStream_t stream) {
    const void* pos  = d_in[0];
    const int*  z    = (const int*)d_in[1];
    // d_in[2] = batch (implicit: graph = i >> 7)
    const void* emb  = d_in[3];
    const void* mw1  = d_in[4];
    const void* mb1  = d_in[5];
    const void* mw2  = d_in[6];
    const void* mb2  = d_in[7];
    const void* l1w  = d_in[8];
    const void* l1b  = d_in[9];
    const void* l2w  = d_in[10];
    const void* l2b  = d_in[11];
    const void* ow1  = d_in[12];
    const void* ob1  = d_in[13];
    const void* ow2  = d_in[14];
    const void* ob2  = d_in[15];

    char* ws = (char*)d_ws;
    const size_t KB = 1024, MB = 1048576;
    int*   w_flag  = (int*)  (ws);
    float* c_pos   = (float*)(ws + 4   * KB);
    float* c_emb   = (float*)(ws + 112 * KB);
    float* c_mb1   = (float*)(ws + 168 * KB);
    float* c_mb2   = (float*)(ws + 172 * KB);
    float* c_l1b   = (float*)(ws + 176 * KB);
    float* c_l2b   = (float*)(ws + 180 * KB);
    float* c_ow1   = (float*)(ws + 184 * KB);
    float* c_ob1   = (float*)(ws + 220 * KB);
    float* c_ow2   = (float*)(ws + 221 * KB);
    float* c_ob2   = (float*)(ws + 222 * KB);
    float* w_gsum  = (float*)(ws + 224 * KB);
    u16*   c_l1wt  = (u16*)  (ws + 256 * KB);
    u16*   c_l2wt  = (u16*)  (ws + 448 * KB);
    u16*   c_mw2t  = (u16*)  (ws + 640 * KB);
    u16*   c_mw1t  = (u16*)  (ws + 832 * KB);
    float* w_dist  = (float*)(ws + 1  * MB);
    float* w_cval  = (float*)(ws + 2  * MB);
    int*   rev_cnt = (int*)  (ws + 3  * MB);
    int*   rev_e   = (int*)  (ws + 4  * MB);
    float* w_h     = (float*)(ws + 8  * MB);
    float* w_xj    = (float*)(ws + 12 * MB);
    float* w_agg   = (float*)(ws + 16 * MB);
    u16*   w_msg   = (u16*)  (ws + 20 * MB);   // 64 MB

    hipMemsetAsync(rev_cnt, 0, NATOMS * sizeof(int), stream);
    hipMemsetAsync(w_gsum, 0, GRAPHS * sizeof(float), stream);

    probe_kernel<<<1, 256, 0, stream>>>((const u16*)emb, w_flag);

    IngestDesc dsc;
    const void* srcs[NARR] = {pos, emb, mb1, mb2, l1b, l2b, ow1, ob1, ow2, ob2};
    void* dsts[NARR] = {c_pos, c_emb, c_mb1, c_mb2, c_l1b, c_l2b, c_ow1, c_ob1,
                        c_ow2, c_ob2};
    int ns[NARR] = {24576, 12800, 768, 768, 768, 768, 8192, 64, 64, 1};
    int total = 0;
    for (int a = 0; a < NARR; ++a) {
        dsc.src[a] = srcs[a]; dsc.dst[a] = dsts[a]; dsc.n[a] = ns[a];
        total += ns[a];
    }
    ingest_kernel<<<(total + 255) / 256, 256, 0, stream>>>(dsc, w_flag, total);
    prep_weights<<<1344, 256, 0, stream>>>(l1w, l2w, mw2, mw1,
                                           c_l1wt, c_l2wt, c_mw2t, c_mw1t, w_flag);

    build_graph_kernel<<<NATOMS / 4, 256, 0, stream>>>(c_pos, w_dist, w_cval,
                                                       rev_cnt, rev_e);
    embed_kernel<<<NATOMS, HID, 0, stream>>>(z, c_emb, w_h);

    for (int l = 0; l < LAYERS; ++l) {
        gemm_mfma<0, 0><<<NATOMS / 32, 256, 0, stream>>>(
            w_h, c_l1wt + (size_t)l * 16384, c_l1b + (size_t)l * 128, w_xj);
        wcompute_kernel<<<NATOMS * KNN / 128, 256, 0, stream>>>(
            w_dist, w_cval, w_xj,
            c_mw1t + (size_t)l * 8192, c_mw2t + (size_t)l * 16384,
            c_mb1 + (size_t)l * 128, c_mb2 + (size_t)l * 128, w_msg);
        gather_kernel<<<NATOMS / 4, 256, 0, stream>>>(rev_cnt, rev_e, w_msg, w_agg);
        gemm_mfma<1, 1><<<NATOMS / 32, 256, 0, stream>>>(
            w_agg, c_l2wt + (size_t)l * 16384, c_l2b + (size_t)l * 128, w_h);
    }

    head_kernel<<<NATOMS / 16, 256, 0, stream>>>(w_h, c_ow1, c_ob1, c_ow2, c_ob2,
                                                 w_gsum);
    finalize_kernel<<<1, GRAPHS, 0, stream>>>(w_gsum, (void*)d_out, w_flag);
}